// Round 7
// baseline (608.924 us; speedup 1.0000x reference)
//
#include <hip/hip_runtime.h>
#include <math.h>

#define N_NODES 100000
#define N_EDGES 3200000
#define BSHIFT 8
#define NPB 256                 // nodes per bucket = 1<<BSHIFT
#define BMASK (NPB - 1)
#define NB 391                  // ceil(N_NODES / NPB)
#define CAP 10240               // bucket capacity (mean 8192, +22 sigma)
#define FC1_GRID 768            // 3 blocks/CU (VGPR-limited), one full round

// ---------------------------------------------------------------------------
// fc1: h1 = relu(x @ W1 + b1)   x:[N,512] f32, W1:[512,16], h1:[N,16]
// Wave handles 4 rows/group, ~8 groups. Software prefetch: next group's x
// loads issue BEFORE current group's compute (hides HBM/L3 latency under
// 512 FMA + 32 ds_read_b128). W1 transposed in LDS; pair-merge butterfly.
// ---------------------------------------------------------------------------
__global__ __launch_bounds__(256, 3) void fc1_kernel(
    const float* __restrict__ x, const float* __restrict__ w,
    const float* __restrict__ b, float* __restrict__ h1) {
  __shared__ float wt[16][512];
  for (int idx = threadIdx.x; idx < 512 * 16; idx += 256) {
    wt[idx & 15][idx >> 4] = w[idx];
  }
  __syncthreads();

  const int lane = threadIdx.x & 63;
  const int wid = blockIdx.x * 4 + (threadIdx.x >> 6);
  const int waves_total = FC1_GRID * 4;
  const float bl = b[lane & 15];
  const int ngroups = N_NODES / 4;  // 25000

  int g = wid;
  if (g >= ngroups) return;

  float4 xa[4][2];
#pragma unroll
  for (int r = 0; r < 4; ++r) {
    const float4* xp = (const float4*)(x + (size_t)(g * 4 + r) * 512 + lane * 4);
    xa[r][0] = xp[0];
    xa[r][1] = xp[64];
  }

  while (true) {
    const int gn = g + waves_total;
    // prefetch next group's rows before touching xa (loads overlap compute)
    float4 xb[4][2];
    if (gn < ngroups) {
#pragma unroll
      for (int r = 0; r < 4; ++r) {
        const float4* xp = (const float4*)(x + (size_t)(gn * 4 + r) * 512 + lane * 4);
        xb[r][0] = xp[0];
        xb[r][1] = xp[64];
      }
    }

    const int r0 = g * 4;
    float acc[4][16];
#pragma unroll
    for (int r = 0; r < 4; ++r)
#pragma unroll
      for (int o = 0; o < 16; ++o) acc[r][o] = 0.f;

#pragma unroll
    for (int o = 0; o < 16; ++o) {
      const float4 w0 = *(const float4*)&wt[o][lane * 4];
      const float4 w1 = *(const float4*)&wt[o][256 + lane * 4];
#pragma unroll
      for (int r = 0; r < 4; ++r) {
        acc[r][o] += xa[r][0].x * w0.x + xa[r][0].y * w0.y +
                     xa[r][0].z * w0.z + xa[r][0].w * w0.w +
                     xa[r][1].x * w1.x + xa[r][1].y * w1.y +
                     xa[r][1].z * w1.z + xa[r][1].w * w1.w;
      }
    }

    const bool b0 = lane & 1, b1 = lane & 2, b2 = lane & 4, b3 = lane & 8;
    float v1r[4];
#pragma unroll
    for (int r = 0; r < 4; ++r) {
      float v8[8];
#pragma unroll
      for (int j = 0; j < 8; ++j) {
        float keep = b0 ? acc[r][2 * j + 1] : acc[r][2 * j];
        float give = b0 ? acc[r][2 * j] : acc[r][2 * j + 1];
        v8[j] = keep + __shfl_xor(give, 1, 64);
      }
      float v4[4];
#pragma unroll
      for (int j = 0; j < 4; ++j) {
        float keep = b1 ? v8[2 * j + 1] : v8[2 * j];
        float give = b1 ? v8[2 * j] : v8[2 * j + 1];
        v4[j] = keep + __shfl_xor(give, 2, 64);
      }
      float v2[2];
#pragma unroll
      for (int j = 0; j < 2; ++j) {
        float keep = b2 ? v4[2 * j + 1] : v4[2 * j];
        float give = b2 ? v4[2 * j] : v4[2 * j + 1];
        v2[j] = keep + __shfl_xor(give, 4, 64);
      }
      float keep = b3 ? v2[1] : v2[0];
      float give = b3 ? v2[0] : v2[1];
      float v1 = keep + __shfl_xor(give, 8, 64);
      v1 += __shfl_xor(v1, 16, 64);
      v1 += __shfl_xor(v1, 32, 64);
      v1r[r] = fmaxf(v1 + bl, 0.f);
    }
    // lanes 0-31 store rows r0+(lane>>4)*1 pairs: 2 stores x 128B contiguous
    if (lane < 32) {
      const int rr = lane >> 4;  // 0..1
      h1[(size_t)(r0 + rr) * 16 + (lane & 15)] = v1r[rr];
      h1[(size_t)(r0 + 2 + rr) * 16 + (lane & 15)] = v1r[2 + rr];
    }

    if (gn >= ngroups) break;
#pragma unroll
    for (int r = 0; r < 4; ++r) {
      xa[r][0] = xb[r][0];
      xa[r][1] = xb[r][1];
    }
    g = gn;
  }
}

// ---------------------------------------------------------------------------
// Bucket scatter: edges grouped by dst>>8, packed (src<<8)|dstlow.
// 256 blocks -> ~32-edge (128B) runs per (block,bucket).
// ---------------------------------------------------------------------------
__global__ __launch_bounds__(256) void stage_kernel(
    const int* __restrict__ src, const int* __restrict__ dst,
    int* __restrict__ gcur, int* __restrict__ staged) {
  __shared__ int hist[NB];
  __shared__ int base[NB];
  const int tid = threadIdx.x;
  for (int i = tid; i < NB; i += 256) hist[i] = 0;
  __syncthreads();

  const int per = (N_EDGES + gridDim.x - 1) / gridDim.x;
  const int e0 = blockIdx.x * per;
  const int e1 = min(e0 + per, N_EDGES);

  for (int e = e0 + tid; e < e1; e += 256) {
    atomicAdd(&hist[dst[e] >> BSHIFT], 1);
  }
  __syncthreads();
  for (int bkt = tid; bkt < NB; bkt += 256) {
    int h = hist[bkt];
    base[bkt] = (h > 0) ? atomicAdd(&gcur[bkt], h) : 0;
    hist[bkt] = 0;  // reuse as local cursor
  }
  __syncthreads();
  for (int e = e0 + tid; e < e1; e += 256) {
    int d = dst[e];
    int s = src[e];
    int bkt = d >> BSHIFT;
    int pos = base[bkt] + atomicAdd(&hist[bkt], 1);
    if (pos < CAP) staged[bkt * CAP + pos] = (s << 8) | (d & BMASK);
  }
}

// ---------------------------------------------------------------------------
// finalize: per bucket, load staged slice into LDS, histogram local dst,
// block-scan -> per-node offs/cnt, scatter src back IN PLACE node-sorted.
// ---------------------------------------------------------------------------
__global__ __launch_bounds__(256) void finalize_kernel(
    int* __restrict__ staged, const int* __restrict__ gcur,
    int* __restrict__ offs, int* __restrict__ cnt) {
  __shared__ int ed[CAP];
  __shared__ int lcnt[NPB];
  __shared__ int lofs[NPB];
  __shared__ int sc[256];
  const int bkt = blockIdx.x, tid = threadIdx.x;
  const int nE = min(gcur[bkt], CAP);
  const int base = bkt * CAP;
  for (int e = tid; e < nE; e += 256) ed[e] = staged[base + e];
  lcnt[tid] = 0;
  __syncthreads();
  for (int e = tid; e < nE; e += 256) atomicAdd(&lcnt[ed[e] & BMASK], 1);
  __syncthreads();
  const int v = lcnt[tid];
  sc[tid] = v;
  __syncthreads();
  for (int d = 1; d < 256; d <<= 1) {
    int add = (tid >= d) ? sc[tid - d] : 0;
    __syncthreads();
    sc[tid] += add;
    __syncthreads();
  }
  const int excl = sc[tid] - v;
  lofs[tid] = excl;
  const int g = bkt * NPB + tid;
  if (g < N_NODES) {
    offs[g] = base + excl;
    cnt[g] = v;
  }
  lcnt[tid] = 0;  // reuse as cursor
  __syncthreads();
  for (int e = tid; e < nE; e += 256) {
    int u = ed[e];
    int dl = u & BMASK;
    int pos = lofs[dl] + atomicAdd(&lcnt[dl], 1);
    staged[base + pos] = u >> 8;  // plain src index, node-sorted
  }
}

// ---------------------------------------------------------------------------
// conv1 (16 -> 32): 8 threads/node = 2 groups x 4 lanes; groups take
// alternating edges; shfl_xor(4) merges groups, masks 1,2 complete the
// k-reduce. Epilogue: h2 quad per lane; t2 = o @ c2llw, 2 dims per lane.
// ---------------------------------------------------------------------------
__global__ __launch_bounds__(256) void conv1_kernel(
    const float* __restrict__ h1, const int* __restrict__ csr,
    const int* __restrict__ offs, const int* __restrict__ cnt,
    const float* __restrict__ llw, const float* __restrict__ llb,
    const float* __restrict__ lrw, const float* __restrict__ c2llw,
    float* __restrict__ h2, float* __restrict__ t2) {
  __shared__ float wl[512], wr[512], w2c[512];
  __shared__ float bb[32];
  for (int idx = threadIdx.x; idx < 512; idx += 256) {
    wl[idx] = llw[idx];
    wr[idx] = lrw[idx];
    w2c[idx] = c2llw[idx];
  }
  if (threadIdx.x < 32) bb[threadIdx.x] = llb[threadIdx.x];
  __syncthreads();

  const int tid = blockIdx.x * 256 + threadIdx.x;
  const int i = tid >> 3;
  if (i >= N_NODES) return;
  const int t8 = threadIdx.x & 7;
  const int gg = t8 >> 2;       // group 0/1
  const int t = t8 & 3;         // dim slice
  const int start = offs[i], deg = cnt[i];

  float4 acc = make_float4(0.f, 0.f, 0.f, 0.f);
  int e = gg;
  int snext = (e < deg) ? csr[start + e] : 0;
  for (; e < deg; e += 2) {
    const int s = snext;
    if (e + 2 < deg) snext = csr[start + e + 2];
    float4 a = *(const float4*)(h1 + (size_t)s * 16 + t * 4);
    acc.x += a.x; acc.y += a.y; acc.z += a.z; acc.w += a.w;
  }
  acc.x += __shfl_xor(acc.x, 4, 64);
  acc.y += __shfl_xor(acc.y, 4, 64);
  acc.z += __shfl_xor(acc.z, 4, 64);
  acc.w += __shfl_xor(acc.w, 4, 64);

  const float inv = 1.f / (float)(deg > 0 ? deg : 1);
  const float4 self = *(const float4*)(h1 + (size_t)i * 16 + t * 4);
  const float mk[4] = {acc.x * inv, acc.y * inv, acc.z * inv, acc.w * inv};
  const float sk[4] = {self.x, self.y, self.z, self.w};

  float4 p[8];
#pragma unroll
  for (int q = 0; q < 8; ++q) p[q] = make_float4(0.f, 0.f, 0.f, 0.f);
#pragma unroll
  for (int j = 0; j < 4; ++j) {
    const int k = 4 * t + j;
#pragma unroll
    for (int q = 0; q < 8; ++q) {
      float4 w4l = *(const float4*)&wl[k * 32 + 4 * q];
      float4 w4r = *(const float4*)&wr[k * 32 + 4 * q];
      p[q].x += mk[j] * w4l.x + sk[j] * w4r.x;
      p[q].y += mk[j] * w4l.y + sk[j] * w4r.y;
      p[q].z += mk[j] * w4l.z + sk[j] * w4r.z;
      p[q].w += mk[j] * w4l.w + sk[j] * w4r.w;
    }
  }
#pragma unroll
  for (int mask = 1; mask <= 2; mask <<= 1) {
#pragma unroll
    for (int q = 0; q < 8; ++q) {
      p[q].x += __shfl_xor(p[q].x, mask, 64);
      p[q].y += __shfl_xor(p[q].y, mask, 64);
      p[q].z += __shfl_xor(p[q].z, mask, 64);
      p[q].w += __shfl_xor(p[q].w, mask, 64);
    }
  }
  float o[32];
#pragma unroll
  for (int q = 0; q < 8; ++q) {
    o[4 * q + 0] = fmaxf(p[q].x + bb[4 * q + 0], 0.f);
    o[4 * q + 1] = fmaxf(p[q].y + bb[4 * q + 1], 0.f);
    o[4 * q + 2] = fmaxf(p[q].z + bb[4 * q + 2], 0.f);
    o[4 * q + 3] = fmaxf(p[q].w + bb[4 * q + 3], 0.f);
  }
  *(float4*)(h2 + (size_t)i * 32 + 4 * t8) =
      make_float4(o[4 * t8], o[4 * t8 + 1], o[4 * t8 + 2], o[4 * t8 + 3]);
  float t0 = 0.f, t1 = 0.f;
#pragma unroll
  for (int k = 0; k < 32; ++k) {
    const float ok = o[k];
    t0 += ok * w2c[k * 16 + 2 * t8];
    t1 += ok * w2c[k * 16 + 2 * t8 + 1];
  }
  *(float2*)(t2 + (size_t)i * 16 + 2 * t8) = make_float2(t0, t1);
}

// ---------------------------------------------------------------------------
// conv2 (pre-transformed, 16-dim agg) + fc2 + head -> d_out.
// 8 threads/node; butterfly masks 1,2,4 -> f[16]; lanes 0..2 emit head.
// ---------------------------------------------------------------------------
__global__ __launch_bounds__(256) void conv2_kernel(
    const float* __restrict__ t2, const float* __restrict__ h2,
    const int* __restrict__ csr, const int* __restrict__ offs,
    const int* __restrict__ cnt, const float* __restrict__ llb,
    const float* __restrict__ lrw, const float* __restrict__ fc2w,
    const float* __restrict__ fc2b, float* __restrict__ out) {
  __shared__ float wr[512];
  __shared__ float bb[16];
  __shared__ float w2[48];
  __shared__ float b2[3];
  for (int idx = threadIdx.x; idx < 512; idx += 256) wr[idx] = lrw[idx];
  if (threadIdx.x < 16) bb[threadIdx.x] = llb[threadIdx.x];
  else if (threadIdx.x >= 64 && threadIdx.x < 112) w2[threadIdx.x - 64] = fc2w[threadIdx.x - 64];
  else if (threadIdx.x >= 128 && threadIdx.x < 131) b2[threadIdx.x - 128] = fc2b[threadIdx.x - 128];
  __syncthreads();

  const int tid = blockIdx.x * 256 + threadIdx.x;
  const int i = tid >> 3;
  if (i >= N_NODES) return;
  const int t8 = threadIdx.x & 7;
  const int gg = t8 >> 2;
  const int t = t8 & 3;
  const int start = offs[i], deg = cnt[i];

  float4 acc = make_float4(0.f, 0.f, 0.f, 0.f);
  int e = gg;
  int snext = (e < deg) ? csr[start + e] : 0;
  for (; e < deg; e += 2) {
    const int s = snext;
    if (e + 2 < deg) snext = csr[start + e + 2];
    float4 a = *(const float4*)(t2 + (size_t)s * 16 + t * 4);
    acc.x += a.x; acc.y += a.y; acc.z += a.z; acc.w += a.w;
  }
  acc.x += __shfl_xor(acc.x, 4, 64);
  acc.y += __shfl_xor(acc.y, 4, 64);
  acc.z += __shfl_xor(acc.z, 4, 64);
  acc.w += __shfl_xor(acc.w, 4, 64);

  const float inv = 1.f / (float)(deg > 0 ? deg : 1);
  const float4 s0 = *(const float4*)(h2 + (size_t)i * 32 + 4 * t8);
  const float sk[4] = {s0.x, s0.y, s0.z, s0.w};
  float4 p[4];
#pragma unroll
  for (int q = 0; q < 4; ++q) p[q] = make_float4(0.f, 0.f, 0.f, 0.f);
#pragma unroll
  for (int kk = 0; kk < 4; ++kk) {
    const int k = 4 * t8 + kk;
    const float s = sk[kk];
#pragma unroll
    for (int q = 0; q < 4; ++q) {
      const float4 wv = *(const float4*)&wr[k * 16 + 4 * q];
      p[q].x += s * wv.x; p[q].y += s * wv.y;
      p[q].z += s * wv.z; p[q].w += s * wv.w;
    }
  }
  if (gg == 0) {
    p[t].x += acc.x * inv; p[t].y += acc.y * inv;
    p[t].z += acc.z * inv; p[t].w += acc.w * inv;
  }
#pragma unroll
  for (int mask = 1; mask <= 4; mask <<= 1) {
#pragma unroll
    for (int q = 0; q < 4; ++q) {
      p[q].x += __shfl_xor(p[q].x, mask, 64);
      p[q].y += __shfl_xor(p[q].y, mask, 64);
      p[q].z += __shfl_xor(p[q].z, mask, 64);
      p[q].w += __shfl_xor(p[q].w, mask, 64);
    }
  }
  if (t8 < 3) {
    float f[16];
#pragma unroll
    for (int q = 0; q < 4; ++q) {
      f[4 * q + 0] = fmaxf(p[q].x + bb[4 * q + 0], 0.f);
      f[4 * q + 1] = fmaxf(p[q].y + bb[4 * q + 1], 0.f);
      f[4 * q + 2] = fmaxf(p[q].z + bb[4 * q + 2], 0.f);
      f[4 * q + 3] = fmaxf(p[q].w + bb[4 * q + 3], 0.f);
    }
    float v0 = b2[0], v1 = b2[1], v2 = b2[2];
#pragma unroll
    for (int k = 0; k < 16; ++k) {
      v0 += f[k] * w2[k * 3 + 0];
      v1 += f[k] * w2[k * 3 + 1];
      v2 += f[k] * w2[k * 3 + 2];
    }
    float gsi = 1.f / (1.f + expf(-v1));
    float mxi = 1.f / (1.f + expf(-v2));
    float fsi = fmaxf(v0, 0.f) + gsi;
    float rv = (t8 == 0) ? fsi : ((t8 == 1) ? gsi : mxi);
    out[(size_t)i * 3 + t8] = rv;
  }
}

extern "C" void kernel_launch(void* const* d_in, const int* in_sizes, int n_in,
                              void* d_out, int out_size, void* d_ws, size_t ws_size,
                              hipStream_t stream) {
  const float* x = (const float*)d_in[0];
  const int* ei = (const int*)d_in[1];
  const float* fc1w = (const float*)d_in[2];
  const float* fc1b = (const float*)d_in[3];
  const float* c1llw = (const float*)d_in[4];
  const float* c1llb = (const float*)d_in[5];
  const float* c1lrw = (const float*)d_in[6];
  const float* c2llw = (const float*)d_in[7];
  const float* c2llb = (const float*)d_in[8];
  const float* c2lrw = (const float*)d_in[9];
  const float* fc2w = (const float*)d_in[10];
  const float* fc2b = (const float*)d_in[11];
  float* outp = (float*)d_out;
  const int* src = ei;
  const int* dst = ei + N_EDGES;

  char* ws = (char*)d_ws;
  float* h1 = (float*)ws;    ws += (size_t)N_NODES * 16 * 4;
  float* h2 = (float*)ws;    ws += (size_t)N_NODES * 32 * 4;
  float* t2 = (float*)ws;    ws += (size_t)N_NODES * 16 * 4;
  int* staged = (int*)ws;    ws += (size_t)NB * CAP * 4;
  int* gcur = (int*)ws;      ws += (size_t)NB * 4;
  int* offs = (int*)ws;      ws += (size_t)N_NODES * 4;
  int* cnt = (int*)ws;       ws += (size_t)N_NODES * 4;
  (void)ws_size; (void)n_in; (void)in_sizes; (void)out_size;

  hipMemsetAsync(gcur, 0, (size_t)NB * 4, stream);
  fc1_kernel<<<FC1_GRID, 256, 0, stream>>>(x, fc1w, fc1b, h1);
  stage_kernel<<<256, 256, 0, stream>>>(src, dst, gcur, staged);
  finalize_kernel<<<NB, 256, 0, stream>>>(staged, gcur, offs, cnt);
  conv1_kernel<<<(N_NODES * 8 + 255) / 256, 256, 0, stream>>>(
      h1, staged, offs, cnt, c1llw, c1llb, c1lrw, c2llw, h2, t2);
  conv2_kernel<<<(N_NODES * 8 + 255) / 256, 256, 0, stream>>>(
      t2, h2, staged, offs, cnt, c2llb, c2lrw, fc2w, fc2b, outp);
}

// Round 8
// 305.878 us; speedup vs baseline: 1.9907x; 1.9907x over previous
//
#include <hip/hip_runtime.h>
#include <math.h>

#define N_NODES 100000
#define N_EDGES 3200000
#define BSHIFT 8
#define NPB 256                 // nodes per bucket = 1<<BSHIFT
#define BMASK (NPB - 1)
#define NB 391                  // ceil(N_NODES / NPB)
#define CAP 10240               // bucket capacity (mean 8192, +22 sigma)
#define FC1_GRID 2048           // 8 blocks/CU requested; LDS caps residency at 5

// ---------------------------------------------------------------------------
// fc1: h1 = relu(x @ W1 + b1)   x:[N,512] f32, W1:[512,16], h1:[N,16]
// R1 structure (no prefetch, no launch_bounds cap -> no spill). Grid 2048
// gives ~5 resident blocks/CU (20 waves/CU) for latency hiding.
// ---------------------------------------------------------------------------
__global__ __launch_bounds__(256) void fc1_kernel(
    const float* __restrict__ x, const float* __restrict__ w,
    const float* __restrict__ b, float* __restrict__ h1) {
  __shared__ float wt[16][512];
  for (int idx = threadIdx.x; idx < 512 * 16; idx += 256) {
    wt[idx & 15][idx >> 4] = w[idx];
  }
  __syncthreads();

  const int lane = threadIdx.x & 63;
  const int wid = blockIdx.x * 4 + (threadIdx.x >> 6);
  const int waves_total = FC1_GRID * 4;
  const float bl = b[lane & 15];
  const int ngroups = N_NODES / 4;  // 25000

  for (int g = wid; g < ngroups; g += waves_total) {
    const int r0 = g * 4;
    float4 xa[4][2];
#pragma unroll
    for (int r = 0; r < 4; ++r) {
      const float4* xp = (const float4*)(x + (size_t)(r0 + r) * 512 + lane * 4);
      xa[r][0] = xp[0];
      xa[r][1] = xp[64];
    }
    float acc[4][16];
#pragma unroll
    for (int r = 0; r < 4; ++r)
#pragma unroll
      for (int o = 0; o < 16; ++o) acc[r][o] = 0.f;

#pragma unroll
    for (int o = 0; o < 16; ++o) {
      const float4 w0 = *(const float4*)&wt[o][lane * 4];
      const float4 w1 = *(const float4*)&wt[o][256 + lane * 4];
#pragma unroll
      for (int r = 0; r < 4; ++r) {
        acc[r][o] += xa[r][0].x * w0.x + xa[r][0].y * w0.y +
                     xa[r][0].z * w0.z + xa[r][0].w * w0.w +
                     xa[r][1].x * w1.x + xa[r][1].y * w1.y +
                     xa[r][1].z * w1.z + xa[r][1].w * w1.w;
      }
    }

    const bool b0 = lane & 1, b1 = lane & 2, b2 = lane & 4, b3 = lane & 8;
#pragma unroll
    for (int r = 0; r < 4; ++r) {
      float v8[8];
#pragma unroll
      for (int j = 0; j < 8; ++j) {
        float keep = b0 ? acc[r][2 * j + 1] : acc[r][2 * j];
        float give = b0 ? acc[r][2 * j] : acc[r][2 * j + 1];
        v8[j] = keep + __shfl_xor(give, 1, 64);
      }
      float v4[4];
#pragma unroll
      for (int j = 0; j < 4; ++j) {
        float keep = b1 ? v8[2 * j + 1] : v8[2 * j];
        float give = b1 ? v8[2 * j] : v8[2 * j + 1];
        v4[j] = keep + __shfl_xor(give, 2, 64);
      }
      float v2[2];
#pragma unroll
      for (int j = 0; j < 2; ++j) {
        float keep = b2 ? v4[2 * j + 1] : v4[2 * j];
        float give = b2 ? v4[2 * j] : v4[2 * j + 1];
        v2[j] = keep + __shfl_xor(give, 4, 64);
      }
      float keep = b3 ? v2[1] : v2[0];
      float give = b3 ? v2[0] : v2[1];
      float v1 = keep + __shfl_xor(give, 8, 64);
      v1 += __shfl_xor(v1, 16, 64);
      v1 += __shfl_xor(v1, 32, 64);
      if (lane < 16) {
        h1[(size_t)(r0 + r) * 16 + lane] = fmaxf(v1 + bl, 0.f);
      }
    }
  }
}

// ---------------------------------------------------------------------------
// Bucket scatter: edges grouped by dst>>8, packed (src<<8)|dstlow.
// 256 blocks -> ~32-edge (128B) runs per (block,bucket).
// ---------------------------------------------------------------------------
__global__ __launch_bounds__(256) void stage_kernel(
    const int* __restrict__ src, const int* __restrict__ dst,
    int* __restrict__ gcur, int* __restrict__ staged) {
  __shared__ int hist[NB];
  __shared__ int base[NB];
  const int tid = threadIdx.x;
  for (int i = tid; i < NB; i += 256) hist[i] = 0;
  __syncthreads();

  const int per = (N_EDGES + gridDim.x - 1) / gridDim.x;
  const int e0 = blockIdx.x * per;
  const int e1 = min(e0 + per, N_EDGES);

  for (int e = e0 + tid; e < e1; e += 256) {
    atomicAdd(&hist[dst[e] >> BSHIFT], 1);
  }
  __syncthreads();
  for (int bkt = tid; bkt < NB; bkt += 256) {
    int h = hist[bkt];
    base[bkt] = (h > 0) ? atomicAdd(&gcur[bkt], h) : 0;
    hist[bkt] = 0;  // reuse as local cursor
  }
  __syncthreads();
  for (int e = e0 + tid; e < e1; e += 256) {
    int d = dst[e];
    int s = src[e];
    int bkt = d >> BSHIFT;
    int pos = base[bkt] + atomicAdd(&hist[bkt], 1);
    if (pos < CAP) staged[bkt * CAP + pos] = (s << 8) | (d & BMASK);
  }
}

// ---------------------------------------------------------------------------
// finalize: per bucket, load staged slice into LDS, histogram local dst,
// block-scan -> per-node offs/cnt, scatter src back IN PLACE node-sorted.
// ---------------------------------------------------------------------------
__global__ __launch_bounds__(256) void finalize_kernel(
    int* __restrict__ staged, const int* __restrict__ gcur,
    int* __restrict__ offs, int* __restrict__ cnt) {
  __shared__ int ed[CAP];
  __shared__ int lcnt[NPB];
  __shared__ int lofs[NPB];
  __shared__ int sc[256];
  const int bkt = blockIdx.x, tid = threadIdx.x;
  const int nE = min(gcur[bkt], CAP);
  const int base = bkt * CAP;
  for (int e = tid; e < nE; e += 256) ed[e] = staged[base + e];
  lcnt[tid] = 0;
  __syncthreads();
  for (int e = tid; e < nE; e += 256) atomicAdd(&lcnt[ed[e] & BMASK], 1);
  __syncthreads();
  const int v = lcnt[tid];
  sc[tid] = v;
  __syncthreads();
  for (int d = 1; d < 256; d <<= 1) {
    int add = (tid >= d) ? sc[tid - d] : 0;
    __syncthreads();
    sc[tid] += add;
    __syncthreads();
  }
  const int excl = sc[tid] - v;
  lofs[tid] = excl;
  const int g = bkt * NPB + tid;
  if (g < N_NODES) {
    offs[g] = base + excl;
    cnt[g] = v;
  }
  lcnt[tid] = 0;  // reuse as cursor
  __syncthreads();
  for (int e = tid; e < nE; e += 256) {
    int u = ed[e];
    int dl = u & BMASK;
    int pos = lofs[dl] + atomicAdd(&lcnt[dl], 1);
    staged[base + pos] = u >> 8;  // plain src index, node-sorted
  }
}

// ---------------------------------------------------------------------------
// conv1 (16 -> 32): 8 threads/node = 2 groups x 4 lanes; groups take
// alternating edges; shfl_xor(4) merges groups, masks 1,2 complete the
// k-reduce. Epilogue: h2 quad per lane; t2 = o @ c2llw, 2 dims per lane.
// ---------------------------------------------------------------------------
__global__ __launch_bounds__(256) void conv1_kernel(
    const float* __restrict__ h1, const int* __restrict__ csr,
    const int* __restrict__ offs, const int* __restrict__ cnt,
    const float* __restrict__ llw, const float* __restrict__ llb,
    const float* __restrict__ lrw, const float* __restrict__ c2llw,
    float* __restrict__ h2, float* __restrict__ t2) {
  __shared__ float wl[512], wr[512], w2c[512];
  __shared__ float bb[32];
  for (int idx = threadIdx.x; idx < 512; idx += 256) {
    wl[idx] = llw[idx];
    wr[idx] = lrw[idx];
    w2c[idx] = c2llw[idx];
  }
  if (threadIdx.x < 32) bb[threadIdx.x] = llb[threadIdx.x];
  __syncthreads();

  const int tid = blockIdx.x * 256 + threadIdx.x;
  const int i = tid >> 3;
  if (i >= N_NODES) return;
  const int t8 = threadIdx.x & 7;
  const int gg = t8 >> 2;       // group 0/1
  const int t = t8 & 3;         // dim slice
  const int start = offs[i], deg = cnt[i];

  float4 acc = make_float4(0.f, 0.f, 0.f, 0.f);
  int e = gg;
  int snext = (e < deg) ? csr[start + e] : 0;
  for (; e < deg; e += 2) {
    const int s = snext;
    if (e + 2 < deg) snext = csr[start + e + 2];
    float4 a = *(const float4*)(h1 + (size_t)s * 16 + t * 4);
    acc.x += a.x; acc.y += a.y; acc.z += a.z; acc.w += a.w;
  }
  acc.x += __shfl_xor(acc.x, 4, 64);
  acc.y += __shfl_xor(acc.y, 4, 64);
  acc.z += __shfl_xor(acc.z, 4, 64);
  acc.w += __shfl_xor(acc.w, 4, 64);

  const float inv = 1.f / (float)(deg > 0 ? deg : 1);
  const float4 self = *(const float4*)(h1 + (size_t)i * 16 + t * 4);
  const float mk[4] = {acc.x * inv, acc.y * inv, acc.z * inv, acc.w * inv};
  const float sk[4] = {self.x, self.y, self.z, self.w};

  float4 p[8];
#pragma unroll
  for (int q = 0; q < 8; ++q) p[q] = make_float4(0.f, 0.f, 0.f, 0.f);
#pragma unroll
  for (int j = 0; j < 4; ++j) {
    const int k = 4 * t + j;
#pragma unroll
    for (int q = 0; q < 8; ++q) {
      float4 w4l = *(const float4*)&wl[k * 32 + 4 * q];
      float4 w4r = *(const float4*)&wr[k * 32 + 4 * q];
      p[q].x += mk[j] * w4l.x + sk[j] * w4r.x;
      p[q].y += mk[j] * w4l.y + sk[j] * w4r.y;
      p[q].z += mk[j] * w4l.z + sk[j] * w4r.z;
      p[q].w += mk[j] * w4l.w + sk[j] * w4r.w;
    }
  }
#pragma unroll
  for (int mask = 1; mask <= 2; mask <<= 1) {
#pragma unroll
    for (int q = 0; q < 8; ++q) {
      p[q].x += __shfl_xor(p[q].x, mask, 64);
      p[q].y += __shfl_xor(p[q].y, mask, 64);
      p[q].z += __shfl_xor(p[q].z, mask, 64);
      p[q].w += __shfl_xor(p[q].w, mask, 64);
    }
  }
  float o[32];
#pragma unroll
  for (int q = 0; q < 8; ++q) {
    o[4 * q + 0] = fmaxf(p[q].x + bb[4 * q + 0], 0.f);
    o[4 * q + 1] = fmaxf(p[q].y + bb[4 * q + 1], 0.f);
    o[4 * q + 2] = fmaxf(p[q].z + bb[4 * q + 2], 0.f);
    o[4 * q + 3] = fmaxf(p[q].w + bb[4 * q + 3], 0.f);
  }
  *(float4*)(h2 + (size_t)i * 32 + 4 * t8) =
      make_float4(o[4 * t8], o[4 * t8 + 1], o[4 * t8 + 2], o[4 * t8 + 3]);
  float t0 = 0.f, t1 = 0.f;
#pragma unroll
  for (int k = 0; k < 32; ++k) {
    const float ok = o[k];
    t0 += ok * w2c[k * 16 + 2 * t8];
    t1 += ok * w2c[k * 16 + 2 * t8 + 1];
  }
  *(float2*)(t2 + (size_t)i * 16 + 2 * t8) = make_float2(t0, t1);
}

// ---------------------------------------------------------------------------
// conv2 (pre-transformed, 16-dim agg) + fc2 + head -> d_out.
// 8 threads/node; butterfly masks 1,2,4 -> f[16]; lanes 0..2 emit head.
// ---------------------------------------------------------------------------
__global__ __launch_bounds__(256) void conv2_kernel(
    const float* __restrict__ t2, const float* __restrict__ h2,
    const int* __restrict__ csr, const int* __restrict__ offs,
    const int* __restrict__ cnt, const float* __restrict__ llb,
    const float* __restrict__ lrw, const float* __restrict__ fc2w,
    const float* __restrict__ fc2b, float* __restrict__ out) {
  __shared__ float wr[512];
  __shared__ float bb[16];
  __shared__ float w2[48];
  __shared__ float b2[3];
  for (int idx = threadIdx.x; idx < 512; idx += 256) wr[idx] = lrw[idx];
  if (threadIdx.x < 16) bb[threadIdx.x] = llb[threadIdx.x];
  else if (threadIdx.x >= 64 && threadIdx.x < 112) w2[threadIdx.x - 64] = fc2w[threadIdx.x - 64];
  else if (threadIdx.x >= 128 && threadIdx.x < 131) b2[threadIdx.x - 128] = fc2b[threadIdx.x - 128];
  __syncthreads();

  const int tid = blockIdx.x * 256 + threadIdx.x;
  const int i = tid >> 3;
  if (i >= N_NODES) return;
  const int t8 = threadIdx.x & 7;
  const int gg = t8 >> 2;
  const int t = t8 & 3;
  const int start = offs[i], deg = cnt[i];

  float4 acc = make_float4(0.f, 0.f, 0.f, 0.f);
  int e = gg;
  int snext = (e < deg) ? csr[start + e] : 0;
  for (; e < deg; e += 2) {
    const int s = snext;
    if (e + 2 < deg) snext = csr[start + e + 2];
    float4 a = *(const float4*)(t2 + (size_t)s * 16 + t * 4);
    acc.x += a.x; acc.y += a.y; acc.z += a.z; acc.w += a.w;
  }
  acc.x += __shfl_xor(acc.x, 4, 64);
  acc.y += __shfl_xor(acc.y, 4, 64);
  acc.z += __shfl_xor(acc.z, 4, 64);
  acc.w += __shfl_xor(acc.w, 4, 64);

  const float inv = 1.f / (float)(deg > 0 ? deg : 1);
  const float4 s0 = *(const float4*)(h2 + (size_t)i * 32 + 4 * t8);
  const float sk[4] = {s0.x, s0.y, s0.z, s0.w};
  float4 p[4];
#pragma unroll
  for (int q = 0; q < 4; ++q) p[q] = make_float4(0.f, 0.f, 0.f, 0.f);
#pragma unroll
  for (int kk = 0; kk < 4; ++kk) {
    const int k = 4 * t8 + kk;
    const float s = sk[kk];
#pragma unroll
    for (int q = 0; q < 4; ++q) {
      const float4 wv = *(const float4*)&wr[k * 16 + 4 * q];
      p[q].x += s * wv.x; p[q].y += s * wv.y;
      p[q].z += s * wv.z; p[q].w += s * wv.w;
    }
  }
  if (gg == 0) {
    p[t].x += acc.x * inv; p[t].y += acc.y * inv;
    p[t].z += acc.z * inv; p[t].w += acc.w * inv;
  }
#pragma unroll
  for (int mask = 1; mask <= 4; mask <<= 1) {
#pragma unroll
    for (int q = 0; q < 4; ++q) {
      p[q].x += __shfl_xor(p[q].x, mask, 64);
      p[q].y += __shfl_xor(p[q].y, mask, 64);
      p[q].z += __shfl_xor(p[q].z, mask, 64);
      p[q].w += __shfl_xor(p[q].w, mask, 64);
    }
  }
  if (t8 < 3) {
    float f[16];
#pragma unroll
    for (int q = 0; q < 4; ++q) {
      f[4 * q + 0] = fmaxf(p[q].x + bb[4 * q + 0], 0.f);
      f[4 * q + 1] = fmaxf(p[q].y + bb[4 * q + 1], 0.f);
      f[4 * q + 2] = fmaxf(p[q].z + bb[4 * q + 2], 0.f);
      f[4 * q + 3] = fmaxf(p[q].w + bb[4 * q + 3], 0.f);
    }
    float v0 = b2[0], v1 = b2[1], v2 = b2[2];
#pragma unroll
    for (int k = 0; k < 16; ++k) {
      v0 += f[k] * w2[k * 3 + 0];
      v1 += f[k] * w2[k * 3 + 1];
      v2 += f[k] * w2[k * 3 + 2];
    }
    float gsi = 1.f / (1.f + expf(-v1));
    float mxi = 1.f / (1.f + expf(-v2));
    float fsi = fmaxf(v0, 0.f) + gsi;
    float rv = (t8 == 0) ? fsi : ((t8 == 1) ? gsi : mxi);
    out[(size_t)i * 3 + t8] = rv;
  }
}

extern "C" void kernel_launch(void* const* d_in, const int* in_sizes, int n_in,
                              void* d_out, int out_size, void* d_ws, size_t ws_size,
                              hipStream_t stream) {
  const float* x = (const float*)d_in[0];
  const int* ei = (const int*)d_in[1];
  const float* fc1w = (const float*)d_in[2];
  const float* fc1b = (const float*)d_in[3];
  const float* c1llw = (const float*)d_in[4];
  const float* c1llb = (const float*)d_in[5];
  const float* c1lrw = (const float*)d_in[6];
  const float* c2llw = (const float*)d_in[7];
  const float* c2llb = (const float*)d_in[8];
  const float* c2lrw = (const float*)d_in[9];
  const float* fc2w = (const float*)d_in[10];
  const float* fc2b = (const float*)d_in[11];
  float* outp = (float*)d_out;
  const int* src = ei;
  const int* dst = ei + N_EDGES;

  char* ws = (char*)d_ws;
  float* h1 = (float*)ws;    ws += (size_t)N_NODES * 16 * 4;
  float* h2 = (float*)ws;    ws += (size_t)N_NODES * 32 * 4;
  float* t2 = (float*)ws;    ws += (size_t)N_NODES * 16 * 4;
  int* staged = (int*)ws;    ws += (size_t)NB * CAP * 4;
  int* gcur = (int*)ws;      ws += (size_t)NB * 4;
  int* offs = (int*)ws;      ws += (size_t)N_NODES * 4;
  int* cnt = (int*)ws;       ws += (size_t)N_NODES * 4;
  (void)ws_size; (void)n_in; (void)in_sizes; (void)out_size;

  hipMemsetAsync(gcur, 0, (size_t)NB * 4, stream);
  fc1_kernel<<<FC1_GRID, 256, 0, stream>>>(x, fc1w, fc1b, h1);
  stage_kernel<<<256, 256, 0, stream>>>(src, dst, gcur, staged);
  finalize_kernel<<<NB, 256, 0, stream>>>(staged, gcur, offs, cnt);
  conv1_kernel<<<(N_NODES * 8 + 255) / 256, 256, 0, stream>>>(
      h1, staged, offs, cnt, c1llw, c1llb, c1lrw, c2llw, h2, t2);
  conv2_kernel<<<(N_NODES * 8 + 255) / 256, 256, 0, stream>>>(
      t2, h2, staged, offs, cnt, c2llb, c2lrw, fc2w, fc2b, outp);
}

// Round 9
// 291.860 us; speedup vs baseline: 2.0864x; 1.0480x over previous
//
#include <hip/hip_runtime.h>
#include <math.h>

#define N_NODES 100000
#define N_EDGES 3200000
#define BSHIFT 8
#define NPB 256                 // nodes per bucket = 1<<BSHIFT
#define BMASK (NPB - 1)
#define NB 391                  // ceil(N_NODES / NPB)
#define CAP 10240               // bucket capacity (mean 8192, +22 sigma)
#define FC1_GRID 512            // 2048 waves, 6250 tiles -> ~3 tiles/wave

typedef __attribute__((ext_vector_type(8))) short short8v;   // 8 bf16 = 4 VGPR
typedef __attribute__((ext_vector_type(4))) float f32x4;     // MFMA C/D

__device__ inline unsigned cvt_pk_bf16(float a, float b) {
  unsigned r;
  asm("v_cvt_pk_bf16_f32 %0, %1, %2" : "=v"(r) : "v"(a), "v"(b));
  return r;
}

// ---------------------------------------------------------------------------
// fc1 via MFMA: h1 = relu(x @ W1 + b1), tiles of 16 rows x 16 outs, K=512 =
// 16 x mfma_f32_16x16x32_bf16. W1 lives in 64 VGPRs of bf16 B-fragments
// (preloaded once per wave) -> no LDS, no shuffles. A-frag: lane l holds
// x[row = l&15][k = (l>>4)*8 + j + 32*step], loaded as 2 float4 + cvt_pk.
// C/D: lane l reg j -> D[(l>>4)*4 + j][l&15]  [m89 mapping].
// ---------------------------------------------------------------------------
__global__ __launch_bounds__(256) void fc1_kernel(
    const float* __restrict__ x, const float* __restrict__ w,
    const float* __restrict__ b, float* __restrict__ h1) {
  const int lane = threadIdx.x & 63;
  const int o = lane & 15;        // output col / A row selector
  const int kb = lane >> 4;       // k-block 0..3
  const int wid = (blockIdx.x * 256 + threadIdx.x) >> 6;
  const int nwaves = FC1_GRID * 4;

  // Preload B fragments: step s, lane holds W[s*32 + kb*8 + j][o], j=0..7.
  short8v bf[16];
#pragma unroll
  for (int s = 0; s < 16; ++s) {
    float wv[8];
#pragma unroll
    for (int j = 0; j < 8; ++j) {
      wv[j] = w[(size_t)(s * 32 + kb * 8 + j) * 16 + o];
    }
    union { unsigned u[4]; short8v v; } pk;
    pk.u[0] = cvt_pk_bf16(wv[0], wv[1]);
    pk.u[1] = cvt_pk_bf16(wv[2], wv[3]);
    pk.u[2] = cvt_pk_bf16(wv[4], wv[5]);
    pk.u[3] = cvt_pk_bf16(wv[6], wv[7]);
    bf[s] = pk.v;
  }
  const float bias = b[o];
  const int ntiles = N_NODES / 16;  // 6250

  for (int tile = wid; tile < ntiles; tile += nwaves) {
    const float* xrow = x + (size_t)(tile * 16 + o) * 512 + kb * 8;
    f32x4 c = {0.f, 0.f, 0.f, 0.f};
#pragma unroll
    for (int s = 0; s < 16; ++s) {
      const float4* xp = (const float4*)(xrow + s * 32);
      float4 a0 = xp[0];
      float4 a1 = xp[1];
      union { unsigned u[4]; short8v v; } fa;
      fa.u[0] = cvt_pk_bf16(a0.x, a0.y);
      fa.u[1] = cvt_pk_bf16(a0.z, a0.w);
      fa.u[2] = cvt_pk_bf16(a1.x, a1.y);
      fa.u[3] = cvt_pk_bf16(a1.z, a1.w);
      c = __builtin_amdgcn_mfma_f32_16x16x32_bf16(fa.v, bf[s], c, 0, 0, 0);
    }
    const int rbase = tile * 16 + (lane >> 4) * 4;
#pragma unroll
    for (int j = 0; j < 4; ++j) {
      h1[(size_t)(rbase + j) * 16 + o] = fmaxf(c[j] + bias, 0.f);
    }
  }
}

// ---------------------------------------------------------------------------
// Bucket scatter: edges grouped by dst>>8, packed (src<<8)|dstlow.
// ---------------------------------------------------------------------------
__global__ __launch_bounds__(256) void stage_kernel(
    const int* __restrict__ src, const int* __restrict__ dst,
    int* __restrict__ gcur, int* __restrict__ staged) {
  __shared__ int hist[NB];
  __shared__ int base[NB];
  const int tid = threadIdx.x;
  for (int i = tid; i < NB; i += 256) hist[i] = 0;
  __syncthreads();

  const int per = (N_EDGES + gridDim.x - 1) / gridDim.x;
  const int e0 = blockIdx.x * per;
  const int e1 = min(e0 + per, N_EDGES);

  for (int e = e0 + tid; e < e1; e += 256) {
    atomicAdd(&hist[dst[e] >> BSHIFT], 1);
  }
  __syncthreads();
  for (int bkt = tid; bkt < NB; bkt += 256) {
    int h = hist[bkt];
    base[bkt] = (h > 0) ? atomicAdd(&gcur[bkt], h) : 0;
    hist[bkt] = 0;  // reuse as local cursor
  }
  __syncthreads();
  for (int e = e0 + tid; e < e1; e += 256) {
    int d = dst[e];
    int s = src[e];
    int bkt = d >> BSHIFT;
    int pos = base[bkt] + atomicAdd(&hist[bkt], 1);
    if (pos < CAP) staged[bkt * CAP + pos] = (s << 8) | (d & BMASK);
  }
}

// ---------------------------------------------------------------------------
// finalize: per bucket, LDS-sort staged slice by local dst; offs/cnt out.
// ---------------------------------------------------------------------------
__global__ __launch_bounds__(256) void finalize_kernel(
    int* __restrict__ staged, const int* __restrict__ gcur,
    int* __restrict__ offs, int* __restrict__ cnt) {
  __shared__ int ed[CAP];
  __shared__ int lcnt[NPB];
  __shared__ int lofs[NPB];
  __shared__ int sc[256];
  const int bkt = blockIdx.x, tid = threadIdx.x;
  const int nE = min(gcur[bkt], CAP);
  const int base = bkt * CAP;
  for (int e = tid; e < nE; e += 256) ed[e] = staged[base + e];
  lcnt[tid] = 0;
  __syncthreads();
  for (int e = tid; e < nE; e += 256) atomicAdd(&lcnt[ed[e] & BMASK], 1);
  __syncthreads();
  const int v = lcnt[tid];
  sc[tid] = v;
  __syncthreads();
  for (int d = 1; d < 256; d <<= 1) {
    int add = (tid >= d) ? sc[tid - d] : 0;
    __syncthreads();
    sc[tid] += add;
    __syncthreads();
  }
  const int excl = sc[tid] - v;
  lofs[tid] = excl;
  const int g = bkt * NPB + tid;
  if (g < N_NODES) {
    offs[g] = base + excl;
    cnt[g] = v;
  }
  lcnt[tid] = 0;  // reuse as cursor
  __syncthreads();
  for (int e = tid; e < nE; e += 256) {
    int u = ed[e];
    int dl = u & BMASK;
    int pos = lofs[dl] + atomicAdd(&lcnt[dl], 1);
    staged[base + pos] = u >> 8;  // plain src index, node-sorted
  }
}

// ---------------------------------------------------------------------------
// conv1 (16 -> 32): 8 threads/node = 2 groups x 4 lanes; epilogue also
// emits t2 = o @ c2llw (pre-transform for conv2).
// ---------------------------------------------------------------------------
__global__ __launch_bounds__(256) void conv1_kernel(
    const float* __restrict__ h1, const int* __restrict__ csr,
    const int* __restrict__ offs, const int* __restrict__ cnt,
    const float* __restrict__ llw, const float* __restrict__ llb,
    const float* __restrict__ lrw, const float* __restrict__ c2llw,
    float* __restrict__ h2, float* __restrict__ t2) {
  __shared__ float wl[512], wr[512], w2c[512];
  __shared__ float bb[32];
  for (int idx = threadIdx.x; idx < 512; idx += 256) {
    wl[idx] = llw[idx];
    wr[idx] = lrw[idx];
    w2c[idx] = c2llw[idx];
  }
  if (threadIdx.x < 32) bb[threadIdx.x] = llb[threadIdx.x];
  __syncthreads();

  const int tid = blockIdx.x * 256 + threadIdx.x;
  const int i = tid >> 3;
  if (i >= N_NODES) return;
  const int t8 = threadIdx.x & 7;
  const int gg = t8 >> 2;       // group 0/1
  const int t = t8 & 3;         // dim slice
  const int start = offs[i], deg = cnt[i];

  float4 acc = make_float4(0.f, 0.f, 0.f, 0.f);
  int e = gg;
  int snext = (e < deg) ? csr[start + e] : 0;
  for (; e < deg; e += 2) {
    const int s = snext;
    if (e + 2 < deg) snext = csr[start + e + 2];
    float4 a = *(const float4*)(h1 + (size_t)s * 16 + t * 4);
    acc.x += a.x; acc.y += a.y; acc.z += a.z; acc.w += a.w;
  }
  acc.x += __shfl_xor(acc.x, 4, 64);
  acc.y += __shfl_xor(acc.y, 4, 64);
  acc.z += __shfl_xor(acc.z, 4, 64);
  acc.w += __shfl_xor(acc.w, 4, 64);

  const float inv = 1.f / (float)(deg > 0 ? deg : 1);
  const float4 self = *(const float4*)(h1 + (size_t)i * 16 + t * 4);
  const float mk[4] = {acc.x * inv, acc.y * inv, acc.z * inv, acc.w * inv};
  const float sk[4] = {self.x, self.y, self.z, self.w};

  float4 p[8];
#pragma unroll
  for (int q = 0; q < 8; ++q) p[q] = make_float4(0.f, 0.f, 0.f, 0.f);
#pragma unroll
  for (int j = 0; j < 4; ++j) {
    const int k = 4 * t + j;
#pragma unroll
    for (int q = 0; q < 8; ++q) {
      float4 w4l = *(const float4*)&wl[k * 32 + 4 * q];
      float4 w4r = *(const float4*)&wr[k * 32 + 4 * q];
      p[q].x += mk[j] * w4l.x + sk[j] * w4r.x;
      p[q].y += mk[j] * w4l.y + sk[j] * w4r.y;
      p[q].z += mk[j] * w4l.z + sk[j] * w4r.z;
      p[q].w += mk[j] * w4l.w + sk[j] * w4r.w;
    }
  }
#pragma unroll
  for (int mask = 1; mask <= 2; mask <<= 1) {
#pragma unroll
    for (int q = 0; q < 8; ++q) {
      p[q].x += __shfl_xor(p[q].x, mask, 64);
      p[q].y += __shfl_xor(p[q].y, mask, 64);
      p[q].z += __shfl_xor(p[q].z, mask, 64);
      p[q].w += __shfl_xor(p[q].w, mask, 64);
    }
  }
  float o[32];
#pragma unroll
  for (int q = 0; q < 8; ++q) {
    o[4 * q + 0] = fmaxf(p[q].x + bb[4 * q + 0], 0.f);
    o[4 * q + 1] = fmaxf(p[q].y + bb[4 * q + 1], 0.f);
    o[4 * q + 2] = fmaxf(p[q].z + bb[4 * q + 2], 0.f);
    o[4 * q + 3] = fmaxf(p[q].w + bb[4 * q + 3], 0.f);
  }
  *(float4*)(h2 + (size_t)i * 32 + 4 * t8) =
      make_float4(o[4 * t8], o[4 * t8 + 1], o[4 * t8 + 2], o[4 * t8 + 3]);
  float t0 = 0.f, t1 = 0.f;
#pragma unroll
  for (int k = 0; k < 32; ++k) {
    const float ok = o[k];
    t0 += ok * w2c[k * 16 + 2 * t8];
    t1 += ok * w2c[k * 16 + 2 * t8 + 1];
  }
  *(float2*)(t2 + (size_t)i * 16 + 2 * t8) = make_float2(t0, t1);
}

// ---------------------------------------------------------------------------
// conv2 (pre-transformed, 16-dim agg) + fc2 + head -> d_out.
// ---------------------------------------------------------------------------
__global__ __launch_bounds__(256) void conv2_kernel(
    const float* __restrict__ t2, const float* __restrict__ h2,
    const int* __restrict__ csr, const int* __restrict__ offs,
    const int* __restrict__ cnt, const float* __restrict__ llb,
    const float* __restrict__ lrw, const float* __restrict__ fc2w,
    const float* __restrict__ fc2b, float* __restrict__ out) {
  __shared__ float wr[512];
  __shared__ float bb[16];
  __shared__ float w2[48];
  __shared__ float b2[3];
  for (int idx = threadIdx.x; idx < 512; idx += 256) wr[idx] = lrw[idx];
  if (threadIdx.x < 16) bb[threadIdx.x] = llb[threadIdx.x];
  else if (threadIdx.x >= 64 && threadIdx.x < 112) w2[threadIdx.x - 64] = fc2w[threadIdx.x - 64];
  else if (threadIdx.x >= 128 && threadIdx.x < 131) b2[threadIdx.x - 128] = fc2b[threadIdx.x - 128];
  __syncthreads();

  const int tid = blockIdx.x * 256 + threadIdx.x;
  const int i = tid >> 3;
  if (i >= N_NODES) return;
  const int t8 = threadIdx.x & 7;
  const int gg = t8 >> 2;
  const int t = t8 & 3;
  const int start = offs[i], deg = cnt[i];

  float4 acc = make_float4(0.f, 0.f, 0.f, 0.f);
  int e = gg;
  int snext = (e < deg) ? csr[start + e] : 0;
  for (; e < deg; e += 2) {
    const int s = snext;
    if (e + 2 < deg) snext = csr[start + e + 2];
    float4 a = *(const float4*)(t2 + (size_t)s * 16 + t * 4);
    acc.x += a.x; acc.y += a.y; acc.z += a.z; acc.w += a.w;
  }
  acc.x += __shfl_xor(acc.x, 4, 64);
  acc.y += __shfl_xor(acc.y, 4, 64);
  acc.z += __shfl_xor(acc.z, 4, 64);
  acc.w += __shfl_xor(acc.w, 4, 64);

  const float inv = 1.f / (float)(deg > 0 ? deg : 1);
  const float4 s0 = *(const float4*)(h2 + (size_t)i * 32 + 4 * t8);
  const float sk[4] = {s0.x, s0.y, s0.z, s0.w};
  float4 p[4];
#pragma unroll
  for (int q = 0; q < 4; ++q) p[q] = make_float4(0.f, 0.f, 0.f, 0.f);
#pragma unroll
  for (int kk = 0; kk < 4; ++kk) {
    const int k = 4 * t8 + kk;
    const float s = sk[kk];
#pragma unroll
    for (int q = 0; q < 4; ++q) {
      const float4 wv = *(const float4*)&wr[k * 16 + 4 * q];
      p[q].x += s * wv.x; p[q].y += s * wv.y;
      p[q].z += s * wv.z; p[q].w += s * wv.w;
    }
  }
  if (gg == 0) {
    p[t].x += acc.x * inv; p[t].y += acc.y * inv;
    p[t].z += acc.z * inv; p[t].w += acc.w * inv;
  }
#pragma unroll
  for (int mask = 1; mask <= 4; mask <<= 1) {
#pragma unroll
    for (int q = 0; q < 4; ++q) {
      p[q].x += __shfl_xor(p[q].x, mask, 64);
      p[q].y += __shfl_xor(p[q].y, mask, 64);
      p[q].z += __shfl_xor(p[q].z, mask, 64);
      p[q].w += __shfl_xor(p[q].w, mask, 64);
    }
  }
  if (t8 < 3) {
    float f[16];
#pragma unroll
    for (int q = 0; q < 4; ++q) {
      f[4 * q + 0] = fmaxf(p[q].x + bb[4 * q + 0], 0.f);
      f[4 * q + 1] = fmaxf(p[q].y + bb[4 * q + 1], 0.f);
      f[4 * q + 2] = fmaxf(p[q].z + bb[4 * q + 2], 0.f);
      f[4 * q + 3] = fmaxf(p[q].w + bb[4 * q + 3], 0.f);
    }
    float v0 = b2[0], v1 = b2[1], v2 = b2[2];
#pragma unroll
    for (int k = 0; k < 16; ++k) {
      v0 += f[k] * w2[k * 3 + 0];
      v1 += f[k] * w2[k * 3 + 1];
      v2 += f[k] * w2[k * 3 + 2];
    }
    float gsi = 1.f / (1.f + expf(-v1));
    float mxi = 1.f / (1.f + expf(-v2));
    float fsi = fmaxf(v0, 0.f) + gsi;
    float rv = (t8 == 0) ? fsi : ((t8 == 1) ? gsi : mxi);
    out[(size_t)i * 3 + t8] = rv;
  }
}

extern "C" void kernel_launch(void* const* d_in, const int* in_sizes, int n_in,
                              void* d_out, int out_size, void* d_ws, size_t ws_size,
                              hipStream_t stream) {
  const float* x = (const float*)d_in[0];
  const int* ei = (const int*)d_in[1];
  const float* fc1w = (const float*)d_in[2];
  const float* fc1b = (const float*)d_in[3];
  const float* c1llw = (const float*)d_in[4];
  const float* c1llb = (const float*)d_in[5];
  const float* c1lrw = (const float*)d_in[6];
  const float* c2llw = (const float*)d_in[7];
  const float* c2llb = (const float*)d_in[8];
  const float* c2lrw = (const float*)d_in[9];
  const float* fc2w = (const float*)d_in[10];
  const float* fc2b = (const float*)d_in[11];
  float* outp = (float*)d_out;
  const int* src = ei;
  const int* dst = ei + N_EDGES;

  char* ws = (char*)d_ws;
  float* h1 = (float*)ws;    ws += (size_t)N_NODES * 16 * 4;
  float* h2 = (float*)ws;    ws += (size_t)N_NODES * 32 * 4;
  float* t2 = (float*)ws;    ws += (size_t)N_NODES * 16 * 4;
  int* staged = (int*)ws;    ws += (size_t)NB * CAP * 4;
  int* gcur = (int*)ws;      ws += (size_t)NB * 4;
  int* offs = (int*)ws;      ws += (size_t)N_NODES * 4;
  int* cnt = (int*)ws;       ws += (size_t)N_NODES * 4;
  (void)ws_size; (void)n_in; (void)in_sizes; (void)out_size;

  hipMemsetAsync(gcur, 0, (size_t)NB * 4, stream);
  fc1_kernel<<<FC1_GRID, 256, 0, stream>>>(x, fc1w, fc1b, h1);
  stage_kernel<<<256, 256, 0, stream>>>(src, dst, gcur, staged);
  finalize_kernel<<<NB, 256, 0, stream>>>(staged, gcur, offs, cnt);
  conv1_kernel<<<(N_NODES * 8 + 255) / 256, 256, 0, stream>>>(
      h1, staged, offs, cnt, c1llw, c1llb, c1lrw, c2llw, h2, t2);
  conv2_kernel<<<(N_NODES * 8 + 255) / 256, 256, 0, stream>>>(
      t2, h2, staged, offs, cnt, c2llb, c2lrw, fc2w, fc2b, outp);
}

// Round 10
// 270.904 us; speedup vs baseline: 2.2477x; 1.0774x over previous
//
#include <hip/hip_runtime.h>
#include <math.h>

#define N_NODES 100000
#define N_EDGES 3200000
#define BSHIFT 8
#define NPB 256                 // nodes per bucket = 1<<BSHIFT
#define BMASK (NPB - 1)
#define NB 391                  // ceil(N_NODES / NPB)
#define CAP 10240               // bucket capacity (mean 8192, +22 sigma)
#define FC1_GRID 512            // 2048 waves, 6250 tiles -> ~3 tiles/wave

typedef __attribute__((ext_vector_type(8))) short short8v;   // 8 bf16 = 4 VGPR
typedef __attribute__((ext_vector_type(4))) float f32x4;     // MFMA C/D

__device__ inline unsigned cvt_pk_bf16(float a, float b) {
  unsigned r;
  asm("v_cvt_pk_bf16_f32 %0, %1, %2" : "=v"(r) : "v"(a), "v"(b));
  return r;
}

// ---------------------------------------------------------------------------
// fc1 via MFMA (R9, proven): tiles of 16 rows x 16 outs, K=512 = 16 x
// mfma_f32_16x16x32_bf16. W1 in 64 VGPRs of bf16 B-frags; no LDS/shuffles.
// ---------------------------------------------------------------------------
__global__ __launch_bounds__(256) void fc1_kernel(
    const float* __restrict__ x, const float* __restrict__ w,
    const float* __restrict__ b, float* __restrict__ h1) {
  const int lane = threadIdx.x & 63;
  const int o = lane & 15;
  const int kb = lane >> 4;
  const int wid = (blockIdx.x * 256 + threadIdx.x) >> 6;
  const int nwaves = FC1_GRID * 4;

  short8v bf[16];
#pragma unroll
  for (int s = 0; s < 16; ++s) {
    float wv[8];
#pragma unroll
    for (int j = 0; j < 8; ++j) {
      wv[j] = w[(size_t)(s * 32 + kb * 8 + j) * 16 + o];
    }
    union { unsigned u[4]; short8v v; } pk;
    pk.u[0] = cvt_pk_bf16(wv[0], wv[1]);
    pk.u[1] = cvt_pk_bf16(wv[2], wv[3]);
    pk.u[2] = cvt_pk_bf16(wv[4], wv[5]);
    pk.u[3] = cvt_pk_bf16(wv[6], wv[7]);
    bf[s] = pk.v;
  }
  const float bias = b[o];
  const int ntiles = N_NODES / 16;  // 6250

  for (int tile = wid; tile < ntiles; tile += nwaves) {
    const float* xrow = x + (size_t)(tile * 16 + o) * 512 + kb * 8;
    f32x4 c = {0.f, 0.f, 0.f, 0.f};
#pragma unroll
    for (int s = 0; s < 16; ++s) {
      const float4* xp = (const float4*)(xrow + s * 32);
      float4 a0 = xp[0];
      float4 a1 = xp[1];
      union { unsigned u[4]; short8v v; } fa;
      fa.u[0] = cvt_pk_bf16(a0.x, a0.y);
      fa.u[1] = cvt_pk_bf16(a0.z, a0.w);
      fa.u[2] = cvt_pk_bf16(a1.x, a1.y);
      fa.u[3] = cvt_pk_bf16(a1.z, a1.w);
      c = __builtin_amdgcn_mfma_f32_16x16x32_bf16(fa.v, bf[s], c, 0, 0, 0);
    }
    const int rbase = tile * 16 + (lane >> 4) * 4;
#pragma unroll
    for (int j = 0; j < 4; ++j) {
      h1[(size_t)(rbase + j) * 16 + o] = fmaxf(c[j] + bias, 0.f);
    }
  }
}

// ---------------------------------------------------------------------------
// Bucket scatter: edges grouped by dst>>8, packed (src<<8)|dstlow.
// ---------------------------------------------------------------------------
__global__ __launch_bounds__(256) void stage_kernel(
    const int* __restrict__ src, const int* __restrict__ dst,
    int* __restrict__ gcur, int* __restrict__ staged) {
  __shared__ int hist[NB];
  __shared__ int base[NB];
  const int tid = threadIdx.x;
  for (int i = tid; i < NB; i += 256) hist[i] = 0;
  __syncthreads();

  const int per = (N_EDGES + gridDim.x - 1) / gridDim.x;
  const int e0 = blockIdx.x * per;
  const int e1 = min(e0 + per, N_EDGES);

  for (int e = e0 + tid; e < e1; e += 256) {
    atomicAdd(&hist[dst[e] >> BSHIFT], 1);
  }
  __syncthreads();
  for (int bkt = tid; bkt < NB; bkt += 256) {
    int h = hist[bkt];
    base[bkt] = (h > 0) ? atomicAdd(&gcur[bkt], h) : 0;
    hist[bkt] = 0;  // reuse as local cursor
  }
  __syncthreads();
  for (int e = e0 + tid; e < e1; e += 256) {
    int d = dst[e];
    int s = src[e];
    int bkt = d >> BSHIFT;
    int pos = base[bkt] + atomicAdd(&hist[bkt], 1);
    if (pos < CAP) staged[bkt * CAP + pos] = (s << 8) | (d & BMASK);
  }
}

// ---------------------------------------------------------------------------
// finalize: per bucket, LDS-sort staged slice by local dst; offs/cnt out.
// ---------------------------------------------------------------------------
__global__ __launch_bounds__(256) void finalize_kernel(
    int* __restrict__ staged, const int* __restrict__ gcur,
    int* __restrict__ offs, int* __restrict__ cnt) {
  __shared__ int ed[CAP];
  __shared__ int lcnt[NPB];
  __shared__ int lofs[NPB];
  __shared__ int sc[256];
  const int bkt = blockIdx.x, tid = threadIdx.x;
  const int nE = min(gcur[bkt], CAP);
  const int base = bkt * CAP;
  for (int e = tid; e < nE; e += 256) ed[e] = staged[base + e];
  lcnt[tid] = 0;
  __syncthreads();
  for (int e = tid; e < nE; e += 256) atomicAdd(&lcnt[ed[e] & BMASK], 1);
  __syncthreads();
  const int v = lcnt[tid];
  sc[tid] = v;
  __syncthreads();
  for (int d = 1; d < 256; d <<= 1) {
    int add = (tid >= d) ? sc[tid - d] : 0;
    __syncthreads();
    sc[tid] += add;
    __syncthreads();
  }
  const int excl = sc[tid] - v;
  lofs[tid] = excl;
  const int g = bkt * NPB + tid;
  if (g < N_NODES) {
    offs[g] = base + excl;
    cnt[g] = v;
  }
  lcnt[tid] = 0;  // reuse as cursor
  __syncthreads();
  for (int e = tid; e < nE; e += 256) {
    int u = ed[e];
    int dl = u & BMASK;
    int pos = lofs[dl] + atomicAdd(&lcnt[dl], 1);
    staged[base + pos] = u >> 8;  // plain src index, node-sorted
  }
}

// ---------------------------------------------------------------------------
// conv1 (16 -> 32): 8 threads/node = 2 groups x 4 lanes. Gather loop is
// 4-deep unrolled: 4 independent csr loads + 4 independent row gathers in
// flight per iteration (MLP 1 -> 4; the serial-latency fix). shfl_xor(4)
// merges groups; masks 1,2 complete the k-reduce. Epilogue: h2 quad/lane,
// t2 = o @ c2llw (pre-transform for conv2) 2 dims/lane.
// ---------------------------------------------------------------------------
__global__ __launch_bounds__(256) void conv1_kernel(
    const float* __restrict__ h1, const int* __restrict__ csr,
    const int* __restrict__ offs, const int* __restrict__ cnt,
    const float* __restrict__ llw, const float* __restrict__ llb,
    const float* __restrict__ lrw, const float* __restrict__ c2llw,
    float* __restrict__ h2, float* __restrict__ t2) {
  __shared__ float wl[512], wr[512], w2c[512];
  __shared__ float bb[32];
  for (int idx = threadIdx.x; idx < 512; idx += 256) {
    wl[idx] = llw[idx];
    wr[idx] = lrw[idx];
    w2c[idx] = c2llw[idx];
  }
  if (threadIdx.x < 32) bb[threadIdx.x] = llb[threadIdx.x];
  __syncthreads();

  const int tid = blockIdx.x * 256 + threadIdx.x;
  const int i = tid >> 3;
  if (i >= N_NODES) return;
  const int t8 = threadIdx.x & 7;
  const int gg = t8 >> 2;       // group 0/1
  const int t = t8 & 3;         // dim slice
  const int start = offs[i], deg = cnt[i];

  float4 acc = make_float4(0.f, 0.f, 0.f, 0.f);
  int e = gg;
  // 4-deep unrolled gather: edges e, e+2, e+4, e+6 for this group
  for (; e + 6 < deg; e += 8) {
    const int s0 = csr[start + e];
    const int s1 = csr[start + e + 2];
    const int s2 = csr[start + e + 4];
    const int s3 = csr[start + e + 6];
    float4 a0 = *(const float4*)(h1 + (size_t)s0 * 16 + t * 4);
    float4 a1 = *(const float4*)(h1 + (size_t)s1 * 16 + t * 4);
    float4 a2 = *(const float4*)(h1 + (size_t)s2 * 16 + t * 4);
    float4 a3 = *(const float4*)(h1 + (size_t)s3 * 16 + t * 4);
    acc.x += (a0.x + a1.x) + (a2.x + a3.x);
    acc.y += (a0.y + a1.y) + (a2.y + a3.y);
    acc.z += (a0.z + a1.z) + (a2.z + a3.z);
    acc.w += (a0.w + a1.w) + (a2.w + a3.w);
  }
  for (; e < deg; e += 2) {
    const int s = csr[start + e];
    float4 a = *(const float4*)(h1 + (size_t)s * 16 + t * 4);
    acc.x += a.x; acc.y += a.y; acc.z += a.z; acc.w += a.w;
  }
  acc.x += __shfl_xor(acc.x, 4, 64);
  acc.y += __shfl_xor(acc.y, 4, 64);
  acc.z += __shfl_xor(acc.z, 4, 64);
  acc.w += __shfl_xor(acc.w, 4, 64);

  const float inv = 1.f / (float)(deg > 0 ? deg : 1);
  const float4 self = *(const float4*)(h1 + (size_t)i * 16 + t * 4);
  const float mk[4] = {acc.x * inv, acc.y * inv, acc.z * inv, acc.w * inv};
  const float sk[4] = {self.x, self.y, self.z, self.w};

  float4 p[8];
#pragma unroll
  for (int q = 0; q < 8; ++q) p[q] = make_float4(0.f, 0.f, 0.f, 0.f);
#pragma unroll
  for (int j = 0; j < 4; ++j) {
    const int k = 4 * t + j;
#pragma unroll
    for (int q = 0; q < 8; ++q) {
      float4 w4l = *(const float4*)&wl[k * 32 + 4 * q];
      float4 w4r = *(const float4*)&wr[k * 32 + 4 * q];
      p[q].x += mk[j] * w4l.x + sk[j] * w4r.x;
      p[q].y += mk[j] * w4l.y + sk[j] * w4r.y;
      p[q].z += mk[j] * w4l.z + sk[j] * w4r.z;
      p[q].w += mk[j] * w4l.w + sk[j] * w4r.w;
    }
  }
#pragma unroll
  for (int mask = 1; mask <= 2; mask <<= 1) {
#pragma unroll
    for (int q = 0; q < 8; ++q) {
      p[q].x += __shfl_xor(p[q].x, mask, 64);
      p[q].y += __shfl_xor(p[q].y, mask, 64);
      p[q].z += __shfl_xor(p[q].z, mask, 64);
      p[q].w += __shfl_xor(p[q].w, mask, 64);
    }
  }
  float o[32];
#pragma unroll
  for (int q = 0; q < 8; ++q) {
    o[4 * q + 0] = fmaxf(p[q].x + bb[4 * q + 0], 0.f);
    o[4 * q + 1] = fmaxf(p[q].y + bb[4 * q + 1], 0.f);
    o[4 * q + 2] = fmaxf(p[q].z + bb[4 * q + 2], 0.f);
    o[4 * q + 3] = fmaxf(p[q].w + bb[4 * q + 3], 0.f);
  }
  *(float4*)(h2 + (size_t)i * 32 + 4 * t8) =
      make_float4(o[4 * t8], o[4 * t8 + 1], o[4 * t8 + 2], o[4 * t8 + 3]);
  float t0 = 0.f, t1 = 0.f;
#pragma unroll
  for (int k = 0; k < 32; ++k) {
    const float ok = o[k];
    t0 += ok * w2c[k * 16 + 2 * t8];
    t1 += ok * w2c[k * 16 + 2 * t8 + 1];
  }
  *(float2*)(t2 + (size_t)i * 16 + 2 * t8) = make_float2(t0, t1);
}

// ---------------------------------------------------------------------------
// conv2 (pre-transformed, 16-dim agg) + fc2 + head -> d_out.
// Same 4-deep unrolled gather; butterfly masks 1,2,4; lanes 0..2 emit head.
// ---------------------------------------------------------------------------
__global__ __launch_bounds__(256) void conv2_kernel(
    const float* __restrict__ t2, const float* __restrict__ h2,
    const int* __restrict__ csr, const int* __restrict__ offs,
    const int* __restrict__ cnt, const float* __restrict__ llb,
    const float* __restrict__ lrw, const float* __restrict__ fc2w,
    const float* __restrict__ fc2b, float* __restrict__ out) {
  __shared__ float wr[512];
  __shared__ float bb[16];
  __shared__ float w2[48];
  __shared__ float b2[3];
  for (int idx = threadIdx.x; idx < 512; idx += 256) wr[idx] = lrw[idx];
  if (threadIdx.x < 16) bb[threadIdx.x] = llb[threadIdx.x];
  else if (threadIdx.x >= 64 && threadIdx.x < 112) w2[threadIdx.x - 64] = fc2w[threadIdx.x - 64];
  else if (threadIdx.x >= 128 && threadIdx.x < 131) b2[threadIdx.x - 128] = fc2b[threadIdx.x - 128];
  __syncthreads();

  const int tid = blockIdx.x * 256 + threadIdx.x;
  const int i = tid >> 3;
  if (i >= N_NODES) return;
  const int t8 = threadIdx.x & 7;
  const int gg = t8 >> 2;
  const int t = t8 & 3;
  const int start = offs[i], deg = cnt[i];

  float4 acc = make_float4(0.f, 0.f, 0.f, 0.f);
  int e = gg;
  for (; e + 6 < deg; e += 8) {
    const int s0 = csr[start + e];
    const int s1 = csr[start + e + 2];
    const int s2 = csr[start + e + 4];
    const int s3 = csr[start + e + 6];
    float4 a0 = *(const float4*)(t2 + (size_t)s0 * 16 + t * 4);
    float4 a1 = *(const float4*)(t2 + (size_t)s1 * 16 + t * 4);
    float4 a2 = *(const float4*)(t2 + (size_t)s2 * 16 + t * 4);
    float4 a3 = *(const float4*)(t2 + (size_t)s3 * 16 + t * 4);
    acc.x += (a0.x + a1.x) + (a2.x + a3.x);
    acc.y += (a0.y + a1.y) + (a2.y + a3.y);
    acc.z += (a0.z + a1.z) + (a2.z + a3.z);
    acc.w += (a0.w + a1.w) + (a2.w + a3.w);
  }
  for (; e < deg; e += 2) {
    const int s = csr[start + e];
    float4 a = *(const float4*)(t2 + (size_t)s * 16 + t * 4);
    acc.x += a.x; acc.y += a.y; acc.z += a.z; acc.w += a.w;
  }
  acc.x += __shfl_xor(acc.x, 4, 64);
  acc.y += __shfl_xor(acc.y, 4, 64);
  acc.z += __shfl_xor(acc.z, 4, 64);
  acc.w += __shfl_xor(acc.w, 4, 64);

  const float inv = 1.f / (float)(deg > 0 ? deg : 1);
  const float4 s0v = *(const float4*)(h2 + (size_t)i * 32 + 4 * t8);
  const float sk[4] = {s0v.x, s0v.y, s0v.z, s0v.w};
  float4 p[4];
#pragma unroll
  for (int q = 0; q < 4; ++q) p[q] = make_float4(0.f, 0.f, 0.f, 0.f);
#pragma unroll
  for (int kk = 0; kk < 4; ++kk) {
    const int k = 4 * t8 + kk;
    const float s = sk[kk];
#pragma unroll
    for (int q = 0; q < 4; ++q) {
      const float4 wv = *(const float4*)&wr[k * 16 + 4 * q];
      p[q].x += s * wv.x; p[q].y += s * wv.y;
      p[q].z += s * wv.z; p[q].w += s * wv.w;
    }
  }
  if (gg == 0) {
    p[t].x += acc.x * inv; p[t].y += acc.y * inv;
    p[t].z += acc.z * inv; p[t].w += acc.w * inv;
  }
#pragma unroll
  for (int mask = 1; mask <= 4; mask <<= 1) {
#pragma unroll
    for (int q = 0; q < 4; ++q) {
      p[q].x += __shfl_xor(p[q].x, mask, 64);
      p[q].y += __shfl_xor(p[q].y, mask, 64);
      p[q].z += __shfl_xor(p[q].z, mask, 64);
      p[q].w += __shfl_xor(p[q].w, mask, 64);
    }
  }
  if (t8 < 3) {
    float f[16];
#pragma unroll
    for (int q = 0; q < 4; ++q) {
      f[4 * q + 0] = fmaxf(p[q].x + bb[4 * q + 0], 0.f);
      f[4 * q + 1] = fmaxf(p[q].y + bb[4 * q + 1], 0.f);
      f[4 * q + 2] = fmaxf(p[q].z + bb[4 * q + 2], 0.f);
      f[4 * q + 3] = fmaxf(p[q].w + bb[4 * q + 3], 0.f);
    }
    float v0 = b2[0], v1 = b2[1], v2 = b2[2];
#pragma unroll
    for (int k = 0; k < 16; ++k) {
      v0 += f[k] * w2[k * 3 + 0];
      v1 += f[k] * w2[k * 3 + 1];
      v2 += f[k] * w2[k * 3 + 2];
    }
    float gsi = 1.f / (1.f + expf(-v1));
    float mxi = 1.f / (1.f + expf(-v2));
    float fsi = fmaxf(v0, 0.f) + gsi;
    float rv = (t8 == 0) ? fsi : ((t8 == 1) ? gsi : mxi);
    out[(size_t)i * 3 + t8] = rv;
  }
}

extern "C" void kernel_launch(void* const* d_in, const int* in_sizes, int n_in,
                              void* d_out, int out_size, void* d_ws, size_t ws_size,
                              hipStream_t stream) {
  const float* x = (const float*)d_in[0];
  const int* ei = (const int*)d_in[1];
  const float* fc1w = (const float*)d_in[2];
  const float* fc1b = (const float*)d_in[3];
  const float* c1llw = (const float*)d_in[4];
  const float* c1llb = (const float*)d_in[5];
  const float* c1lrw = (const float*)d_in[6];
  const float* c2llw = (const float*)d_in[7];
  const float* c2llb = (const float*)d_in[8];
  const float* c2lrw = (const float*)d_in[9];
  const float* fc2w = (const float*)d_in[10];
  const float* fc2b = (const float*)d_in[11];
  float* outp = (float*)d_out;
  const int* src = ei;
  const int* dst = ei + N_EDGES;

  char* ws = (char*)d_ws;
  float* h1 = (float*)ws;    ws += (size_t)N_NODES * 16 * 4;
  float* h2 = (float*)ws;    ws += (size_t)N_NODES * 32 * 4;
  float* t2 = (float*)ws;    ws += (size_t)N_NODES * 16 * 4;
  int* staged = (int*)ws;    ws += (size_t)NB * CAP * 4;
  int* gcur = (int*)ws;      ws += (size_t)NB * 4;
  int* offs = (int*)ws;      ws += (size_t)N_NODES * 4;
  int* cnt = (int*)ws;       ws += (size_t)N_NODES * 4;
  (void)ws_size; (void)n_in; (void)in_sizes; (void)out_size;

  hipMemsetAsync(gcur, 0, (size_t)NB * 4, stream);
  fc1_kernel<<<FC1_GRID, 256, 0, stream>>>(x, fc1w, fc1b, h1);
  stage_kernel<<<256, 256, 0, stream>>>(src, dst, gcur, staged);
  finalize_kernel<<<NB, 256, 0, stream>>>(staged, gcur, offs, cnt);
  conv1_kernel<<<(N_NODES * 8 + 255) / 256, 256, 0, stream>>>(
      h1, staged, offs, cnt, c1llw, c1llb, c1lrw, c2llw, h2, t2);
  conv2_kernel<<<(N_NODES * 8 + 255) / 256, 256, 0, stream>>>(
      t2, h2, staged, offs, cnt, c2llb, c2lrw, fc2w, fc2b, outp);
}

// Round 12
// 238.553 us; speedup vs baseline: 2.5526x; 1.1356x over previous
//
#include <hip/hip_runtime.h>
#include <math.h>

#define N_NODES 100000
#define N_EDGES 3200000
#define BSHIFT 8
#define NPB 256                 // nodes per bucket = 1<<BSHIFT
#define BMASK (NPB - 1)
#define NB 391                  // ceil(N_NODES / NPB)
#define CAP 10240               // bucket capacity (mean 8192, +22 sigma)
#define FC1_GRID 512            // 2048 waves, 6250 tiles -> ~3 tiles/wave

typedef __attribute__((ext_vector_type(8))) short short8v;   // 8 bf16 = 4 VGPR
typedef __attribute__((ext_vector_type(4))) float f32x4;     // MFMA C/D

__device__ inline unsigned cvt_pk_bf16(float a, float b) {
  unsigned r;
  asm("v_cvt_pk_bf16_f32 %0, %1, %2" : "=v"(r) : "v"(a), "v"(b));
  return r;
}
__device__ inline unsigned short f32_to_bf16(float f) {
  union { float f; unsigned u; } v; v.f = f;
  unsigned r = v.u + 0x7fff + ((v.u >> 16) & 1);   // RNE
  return (unsigned short)(r >> 16);
}
__device__ inline float bf16_to_f32(unsigned short h) {
  union { unsigned u; float f; } v; v.u = ((unsigned)h) << 16;
  return v.f;
}

// ---------------------------------------------------------------------------
// fc1 via MFMA: tiles of 16 rows x 16 outs, K=512 = 16 x mfma 16x16x32 bf16.
// W1 in 64 VGPRs of bf16 B-frags; no LDS/shuffles. h1 stored BF16 (32B rows
// -> 3.2MB total, fits every XCD L2 for conv1's gathers).
// ---------------------------------------------------------------------------
__global__ __launch_bounds__(256) void fc1_kernel(
    const float* __restrict__ x, const float* __restrict__ w,
    const float* __restrict__ b, unsigned short* __restrict__ h1) {
  const int lane = threadIdx.x & 63;
  const int o = lane & 15;
  const int kb = lane >> 4;
  const int wid = (blockIdx.x * 256 + threadIdx.x) >> 6;
  const int nwaves = FC1_GRID * 4;

  short8v bf[16];
#pragma unroll
  for (int s = 0; s < 16; ++s) {
    float wv[8];
#pragma unroll
    for (int j = 0; j < 8; ++j) {
      wv[j] = w[(size_t)(s * 32 + kb * 8 + j) * 16 + o];
    }
    union { unsigned u[4]; short8v v; } pk;
    pk.u[0] = cvt_pk_bf16(wv[0], wv[1]);
    pk.u[1] = cvt_pk_bf16(wv[2], wv[3]);
    pk.u[2] = cvt_pk_bf16(wv[4], wv[5]);
    pk.u[3] = cvt_pk_bf16(wv[6], wv[7]);
    bf[s] = pk.v;
  }
  const float bias = b[o];
  const int ntiles = N_NODES / 16;  // 6250

  for (int tile = wid; tile < ntiles; tile += nwaves) {
    const float* xrow = x + (size_t)(tile * 16 + o) * 512 + kb * 8;
    f32x4 c = {0.f, 0.f, 0.f, 0.f};
#pragma unroll
    for (int s = 0; s < 16; ++s) {
      const float4* xp = (const float4*)(xrow + s * 32);
      float4 a0 = xp[0];
      float4 a1 = xp[1];
      union { unsigned u[4]; short8v v; } fa;
      fa.u[0] = cvt_pk_bf16(a0.x, a0.y);
      fa.u[1] = cvt_pk_bf16(a0.z, a0.w);
      fa.u[2] = cvt_pk_bf16(a1.x, a1.y);
      fa.u[3] = cvt_pk_bf16(a1.z, a1.w);
      c = __builtin_amdgcn_mfma_f32_16x16x32_bf16(fa.v, bf[s], c, 0, 0, 0);
    }
    const int rbase = tile * 16 + (lane >> 4) * 4;
#pragma unroll
    for (int j = 0; j < 4; ++j) {
      h1[(size_t)(rbase + j) * 16 + o] = f32_to_bf16(fmaxf(c[j] + bias, 0.f));
    }
  }
}

// ---------------------------------------------------------------------------
// Bucket scatter: edges grouped by dst>>8, packed (src<<8)|dstlow.
// ---------------------------------------------------------------------------
__global__ __launch_bounds__(256) void stage_kernel(
    const int* __restrict__ src, const int* __restrict__ dst,
    int* __restrict__ gcur, int* __restrict__ staged) {
  __shared__ int hist[NB];
  __shared__ int base[NB];
  const int tid = threadIdx.x;
  for (int i = tid; i < NB; i += 256) hist[i] = 0;
  __syncthreads();

  const int per = (N_EDGES + gridDim.x - 1) / gridDim.x;
  const int e0 = blockIdx.x * per;
  const int e1 = min(e0 + per, N_EDGES);

  for (int e = e0 + tid; e < e1; e += 256) {
    atomicAdd(&hist[dst[e] >> BSHIFT], 1);
  }
  __syncthreads();
  for (int bkt = tid; bkt < NB; bkt += 256) {
    int h = hist[bkt];
    base[bkt] = (h > 0) ? atomicAdd(&gcur[bkt], h) : 0;
    hist[bkt] = 0;  // reuse as local cursor
  }
  __syncthreads();
  for (int e = e0 + tid; e < e1; e += 256) {
    int d = dst[e];
    int s = src[e];
    int bkt = d >> BSHIFT;
    int pos = base[bkt] + atomicAdd(&hist[bkt], 1);
    if (pos < CAP) staged[bkt * CAP + pos] = (s << 8) | (d & BMASK);
  }
}

// ---------------------------------------------------------------------------
// finalize: per bucket, LDS-sort staged slice by local dst; offs/cnt out.
// ---------------------------------------------------------------------------
__global__ __launch_bounds__(256) void finalize_kernel(
    int* __restrict__ staged, const int* __restrict__ gcur,
    int* __restrict__ offs, int* __restrict__ cnt) {
  __shared__ int ed[CAP];
  __shared__ int lcnt[NPB];
  __shared__ int lofs[NPB];
  __shared__ int sc[256];
  const int bkt = blockIdx.x, tid = threadIdx.x;
  const int nE = min(gcur[bkt], CAP);
  const int base = bkt * CAP;
  for (int e = tid; e < nE; e += 256) ed[e] = staged[base + e];
  lcnt[tid] = 0;
  __syncthreads();
  for (int e = tid; e < nE; e += 256) atomicAdd(&lcnt[ed[e] & BMASK], 1);
  __syncthreads();
  const int v = lcnt[tid];
  sc[tid] = v;
  __syncthreads();
  for (int d = 1; d < 256; d <<= 1) {
    int add = (tid >= d) ? sc[tid - d] : 0;
    __syncthreads();
    sc[tid] += add;
    __syncthreads();
  }
  const int excl = sc[tid] - v;
  lofs[tid] = excl;
  const int g = bkt * NPB + tid;
  if (g < N_NODES) {
    offs[g] = base + excl;
    cnt[g] = v;
  }
  lcnt[tid] = 0;  // reuse as cursor
  __syncthreads();
  for (int e = tid; e < nE; e += 256) {
    int u = ed[e];
    int dl = u & BMASK;
    int pos = lofs[dl] + atomicAdd(&lcnt[dl], 1);
    staged[base + pos] = u >> 8;  // plain src index, node-sorted
  }
}

// ---------------------------------------------------------------------------
// conv1 (16 -> 32): 8 threads/node, 4-deep unrolled bf16 gather (8B/lane,
// 32B/row -> L2-resident h1). Weight LDS stores quad Q of row k at position
// Q^(k>>2); the read fetches original quad q from 4*(q^t) and accumulates
// into p[q] (R11 bug: accumulated into p[q^t] -- data right, slot wrong).
// ---------------------------------------------------------------------------
__global__ __launch_bounds__(256) void conv1_kernel(
    const unsigned short* __restrict__ h1, const int* __restrict__ csr,
    const int* __restrict__ offs, const int* __restrict__ cnt,
    const float* __restrict__ llw, const float* __restrict__ llb,
    const float* __restrict__ lrw, const float* __restrict__ c2llw,
    float* __restrict__ h2, unsigned short* __restrict__ t2) {
  __shared__ float wl[512], wr[512], w2c[512];
  __shared__ float bb[32];
  for (int idx = threadIdx.x; idx < 512; idx += 256) {
    const int k = idx >> 5, jj = idx & 31;
    const int sj = 4 * ((jj >> 2) ^ (k >> 2)) + (jj & 3);  // swizzle store
    wl[k * 32 + sj] = llw[idx];
    wr[k * 32 + sj] = lrw[idx];
    w2c[idx] = c2llw[idx];  // unswizzled
  }
  if (threadIdx.x < 32) bb[threadIdx.x] = llb[threadIdx.x];
  __syncthreads();

  const int tid = blockIdx.x * 256 + threadIdx.x;
  const int i = tid >> 3;
  if (i >= N_NODES) return;
  const int t8 = threadIdx.x & 7;
  const int gg = t8 >> 2;       // group 0/1
  const int t = t8 & 3;         // dim slice
  const int start = offs[i], deg = cnt[i];

  float4 acc = make_float4(0.f, 0.f, 0.f, 0.f);
  int e = gg;
  for (; e + 6 < deg; e += 8) {
    const int s0 = csr[start + e];
    const int s1 = csr[start + e + 2];
    const int s2 = csr[start + e + 4];
    const int s3 = csr[start + e + 6];
    ushort4 a0 = *(const ushort4*)(h1 + (size_t)s0 * 16 + t * 4);
    ushort4 a1 = *(const ushort4*)(h1 + (size_t)s1 * 16 + t * 4);
    ushort4 a2 = *(const ushort4*)(h1 + (size_t)s2 * 16 + t * 4);
    ushort4 a3 = *(const ushort4*)(h1 + (size_t)s3 * 16 + t * 4);
    acc.x += (bf16_to_f32(a0.x) + bf16_to_f32(a1.x)) +
             (bf16_to_f32(a2.x) + bf16_to_f32(a3.x));
    acc.y += (bf16_to_f32(a0.y) + bf16_to_f32(a1.y)) +
             (bf16_to_f32(a2.y) + bf16_to_f32(a3.y));
    acc.z += (bf16_to_f32(a0.z) + bf16_to_f32(a1.z)) +
             (bf16_to_f32(a2.z) + bf16_to_f32(a3.z));
    acc.w += (bf16_to_f32(a0.w) + bf16_to_f32(a1.w)) +
             (bf16_to_f32(a2.w) + bf16_to_f32(a3.w));
  }
  for (; e < deg; e += 2) {
    const int s = csr[start + e];
    ushort4 a = *(const ushort4*)(h1 + (size_t)s * 16 + t * 4);
    acc.x += bf16_to_f32(a.x); acc.y += bf16_to_f32(a.y);
    acc.z += bf16_to_f32(a.z); acc.w += bf16_to_f32(a.w);
  }
  acc.x += __shfl_xor(acc.x, 4, 64);
  acc.y += __shfl_xor(acc.y, 4, 64);
  acc.z += __shfl_xor(acc.z, 4, 64);
  acc.w += __shfl_xor(acc.w, 4, 64);

  const float inv = 1.f / (float)(deg > 0 ? deg : 1);
  const ushort4 selfu = *(const ushort4*)(h1 + (size_t)i * 16 + t * 4);
  const float mk[4] = {acc.x * inv, acc.y * inv, acc.z * inv, acc.w * inv};
  const float sk[4] = {bf16_to_f32(selfu.x), bf16_to_f32(selfu.y),
                       bf16_to_f32(selfu.z), bf16_to_f32(selfu.w)};

  float4 p[8];
#pragma unroll
  for (int q = 0; q < 8; ++q) p[q] = make_float4(0.f, 0.f, 0.f, 0.f);
#pragma unroll
  for (int j = 0; j < 4; ++j) {
    const int k = 4 * t + j;          // k>>2 == t
#pragma unroll
    for (int q = 0; q < 8; ++q) {
      const int qs = 4 * (q ^ t);     // swizzled position of original quad q
      float4 w4l = *(const float4*)&wl[k * 32 + qs];
      float4 w4r = *(const float4*)&wr[k * 32 + qs];
      p[q].x += mk[j] * w4l.x + sk[j] * w4r.x;
      p[q].y += mk[j] * w4l.y + sk[j] * w4r.y;
      p[q].z += mk[j] * w4l.z + sk[j] * w4r.z;
      p[q].w += mk[j] * w4l.w + sk[j] * w4r.w;
    }
  }
#pragma unroll
  for (int mask = 1; mask <= 2; mask <<= 1) {
#pragma unroll
    for (int q = 0; q < 8; ++q) {
      p[q].x += __shfl_xor(p[q].x, mask, 64);
      p[q].y += __shfl_xor(p[q].y, mask, 64);
      p[q].z += __shfl_xor(p[q].z, mask, 64);
      p[q].w += __shfl_xor(p[q].w, mask, 64);
    }
  }
  float o[32];
#pragma unroll
  for (int q = 0; q < 8; ++q) {
    o[4 * q + 0] = fmaxf(p[q].x + bb[4 * q + 0], 0.f);
    o[4 * q + 1] = fmaxf(p[q].y + bb[4 * q + 1], 0.f);
    o[4 * q + 2] = fmaxf(p[q].z + bb[4 * q + 2], 0.f);
    o[4 * q + 3] = fmaxf(p[q].w + bb[4 * q + 3], 0.f);
  }
  *(float4*)(h2 + (size_t)i * 32 + 4 * t8) =
      make_float4(o[4 * t8], o[4 * t8 + 1], o[4 * t8 + 2], o[4 * t8 + 3]);
  float t0 = 0.f, t1 = 0.f;
#pragma unroll
  for (int k = 0; k < 32; ++k) {
    const float ok = o[k];
    t0 += ok * w2c[k * 16 + 2 * t8];
    t1 += ok * w2c[k * 16 + 2 * t8 + 1];
  }
  *(unsigned*)(t2 + (size_t)i * 16 + 2 * t8) = cvt_pk_bf16(t0, t1);
}

// ---------------------------------------------------------------------------
// conv2 (pre-transformed bf16 t2, 16-dim agg) + fc2 + head -> d_out.
// Same swizzle discipline: read original quad q from 4*(q^(t8&3)),
// accumulate into p[q].
// ---------------------------------------------------------------------------
__global__ __launch_bounds__(256) void conv2_kernel(
    const unsigned short* __restrict__ t2, const float* __restrict__ h2,
    const int* __restrict__ csr, const int* __restrict__ offs,
    const int* __restrict__ cnt, const float* __restrict__ llb,
    const float* __restrict__ lrw, const float* __restrict__ fc2w,
    const float* __restrict__ fc2b, float* __restrict__ out) {
  __shared__ float wr[512];
  __shared__ float bb[16];
  __shared__ float w2[48];
  __shared__ float b2[3];
  for (int idx = threadIdx.x; idx < 512; idx += 256) {
    const int k = idx >> 4, jj = idx & 15;
    const int sj = 4 * ((jj >> 2) ^ ((k >> 2) & 3)) + (jj & 3);  // swizzle
    wr[k * 16 + sj] = lrw[idx];
  }
  if (threadIdx.x < 16) bb[threadIdx.x] = llb[threadIdx.x];
  else if (threadIdx.x >= 64 && threadIdx.x < 112) w2[threadIdx.x - 64] = fc2w[threadIdx.x - 64];
  else if (threadIdx.x >= 128 && threadIdx.x < 131) b2[threadIdx.x - 128] = fc2b[threadIdx.x - 128];
  __syncthreads();

  const int tid = blockIdx.x * 256 + threadIdx.x;
  const int i = tid >> 3;
  if (i >= N_NODES) return;
  const int t8 = threadIdx.x & 7;
  const int gg = t8 >> 2;
  const int t = t8 & 3;
  const int start = offs[i], deg = cnt[i];

  float4 acc = make_float4(0.f, 0.f, 0.f, 0.f);
  int e = gg;
  for (; e + 6 < deg; e += 8) {
    const int s0 = csr[start + e];
    const int s1 = csr[start + e + 2];
    const int s2 = csr[start + e + 4];
    const int s3 = csr[start + e + 6];
    ushort4 a0 = *(const ushort4*)(t2 + (size_t)s0 * 16 + t * 4);
    ushort4 a1 = *(const ushort4*)(t2 + (size_t)s1 * 16 + t * 4);
    ushort4 a2 = *(const ushort4*)(t2 + (size_t)s2 * 16 + t * 4);
    ushort4 a3 = *(const ushort4*)(t2 + (size_t)s3 * 16 + t * 4);
    acc.x += (bf16_to_f32(a0.x) + bf16_to_f32(a1.x)) +
             (bf16_to_f32(a2.x) + bf16_to_f32(a3.x));
    acc.y += (bf16_to_f32(a0.y) + bf16_to_f32(a1.y)) +
             (bf16_to_f32(a2.y) + bf16_to_f32(a3.y));
    acc.z += (bf16_to_f32(a0.z) + bf16_to_f32(a1.z)) +
             (bf16_to_f32(a2.z) + bf16_to_f32(a3.z));
    acc.w += (bf16_to_f32(a0.w) + bf16_to_f32(a1.w)) +
             (bf16_to_f32(a2.w) + bf16_to_f32(a3.w));
  }
  for (; e < deg; e += 2) {
    const int s = csr[start + e];
    ushort4 a = *(const ushort4*)(t2 + (size_t)s * 16 + t * 4);
    acc.x += bf16_to_f32(a.x); acc.y += bf16_to_f32(a.y);
    acc.z += bf16_to_f32(a.z); acc.w += bf16_to_f32(a.w);
  }
  acc.x += __shfl_xor(acc.x, 4, 64);
  acc.y += __shfl_xor(acc.y, 4, 64);
  acc.z += __shfl_xor(acc.z, 4, 64);
  acc.w += __shfl_xor(acc.w, 4, 64);

  const float inv = 1.f / (float)(deg > 0 ? deg : 1);
  const float4 s0v = *(const float4*)(h2 + (size_t)i * 32 + 4 * t8);
  const float sk[4] = {s0v.x, s0v.y, s0v.z, s0v.w};
  float4 p[4];
#pragma unroll
  for (int q = 0; q < 4; ++q) p[q] = make_float4(0.f, 0.f, 0.f, 0.f);
#pragma unroll
  for (int kk = 0; kk < 4; ++kk) {
    const int k = 4 * t8 + kk;        // (k>>2)&3 == t8&3
    const float s = sk[kk];
#pragma unroll
    for (int q = 0; q < 4; ++q) {
      const int qs = 4 * (q ^ (t8 & 3));  // swizzled position of quad q
      const float4 wv = *(const float4*)&wr[k * 16 + qs];
      p[q].x += s * wv.x; p[q].y += s * wv.y;
      p[q].z += s * wv.z; p[q].w += s * wv.w;
    }
  }
  if (gg == 0) {
    p[t].x += acc.x * inv; p[t].y += acc.y * inv;
    p[t].z += acc.z * inv; p[t].w += acc.w * inv;
  }
#pragma unroll
  for (int mask = 1; mask <= 4; mask <<= 1) {
#pragma unroll
    for (int q = 0; q < 4; ++q) {
      p[q].x += __shfl_xor(p[q].x, mask, 64);
      p[q].y += __shfl_xor(p[q].y, mask, 64);
      p[q].z += __shfl_xor(p[q].z, mask, 64);
      p[q].w += __shfl_xor(p[q].w, mask, 64);
    }
  }
  if (t8 < 3) {
    float f[16];
#pragma unroll
    for (int q = 0; q < 4; ++q) {
      f[4 * q + 0] = fmaxf(p[q].x + bb[4 * q + 0], 0.f);
      f[4 * q + 1] = fmaxf(p[q].y + bb[4 * q + 1], 0.f);
      f[4 * q + 2] = fmaxf(p[q].z + bb[4 * q + 2], 0.f);
      f[4 * q + 3] = fmaxf(p[q].w + bb[4 * q + 3], 0.f);
    }
    float v0 = b2[0], v1 = b2[1], v2 = b2[2];
#pragma unroll
    for (int k = 0; k < 16; ++k) {
      v0 += f[k] * w2[k * 3 + 0];
      v1 += f[k] * w2[k * 3 + 1];
      v2 += f[k] * w2[k * 3 + 2];
    }
    float gsi = 1.f / (1.f + expf(-v1));
    float mxi = 1.f / (1.f + expf(-v2));
    float fsi = fmaxf(v0, 0.f) + gsi;
    float rv = (t8 == 0) ? fsi : ((t8 == 1) ? gsi : mxi);
    out[(size_t)i * 3 + t8] = rv;
  }
}

extern "C" void kernel_launch(void* const* d_in, const int* in_sizes, int n_in,
                              void* d_out, int out_size, void* d_ws, size_t ws_size,
                              hipStream_t stream) {
  const float* x = (const float*)d_in[0];
  const int* ei = (const int*)d_in[1];
  const float* fc1w = (const float*)d_in[2];
  const float* fc1b = (const float*)d_in[3];
  const float* c1llw = (const float*)d_in[4];
  const float* c1llb = (const float*)d_in[5];
  const float* c1lrw = (const float*)d_in[6];
  const float* c2llw = (const float*)d_in[7];
  const float* c2llb = (const float*)d_in[8];
  const float* c2lrw = (const float*)d_in[9];
  const float* fc2w = (const float*)d_in[10];
  const float* fc2b = (const float*)d_in[11];
  float* outp = (float*)d_out;
  const int* src = ei;
  const int* dst = ei + N_EDGES;

  char* ws = (char*)d_ws;
  unsigned short* h1 = (unsigned short*)ws;  ws += (size_t)N_NODES * 16 * 2;
  float* h2 = (float*)ws;                    ws += (size_t)N_NODES * 32 * 4;
  unsigned short* t2 = (unsigned short*)ws;  ws += (size_t)N_NODES * 16 * 2;
  int* staged = (int*)ws;                    ws += (size_t)NB * CAP * 4;
  int* gcur = (int*)ws;                      ws += (size_t)NB * 4;
  int* offs = (int*)ws;                      ws += (size_t)N_NODES * 4;
  int* cnt = (int*)ws;                       ws += (size_t)N_NODES * 4;
  (void)ws_size; (void)n_in; (void)in_sizes; (void)out_size;

  hipMemsetAsync(gcur, 0, (size_t)NB * 4, stream);
  fc1_kernel<<<FC1_GRID, 256, 0, stream>>>(x, fc1w, fc1b, h1);
  stage_kernel<<<256, 256, 0, stream>>>(src, dst, gcur, staged);
  finalize_kernel<<<NB, 256, 0, stream>>>(staged, gcur, offs, cnt);
  conv1_kernel<<<(N_NODES * 8 + 255) / 256, 256, 0, stream>>>(
      h1, staged, offs, cnt, c1llw, c1llb, c1lrw, c2llw, h2, t2);
  conv2_kernel<<<(N_NODES * 8 + 255) / 256, 256, 0, stream>>>(
      t2, h2, staged, offs, cnt, c2llb, c2lrw, fc2w, fc2b, outp);
}

// Round 13
// 216.496 us; speedup vs baseline: 2.8126x; 1.1019x over previous
//
#include <hip/hip_runtime.h>
#include <math.h>

#define N_NODES 100000
#define N_EDGES 3200000
#define BSHIFT 8
#define NPB 256                 // nodes per bucket = 1<<BSHIFT
#define BMASK (NPB - 1)
#define NB 391                  // ceil(N_NODES / NPB)
#define CAP 10240               // bucket capacity (mean 8192, +22 sigma)
#define FC1_BLOCKS 512          // fc1 half of the fused kernel
#define STG_BLOCKS 256          // stage half

typedef __attribute__((ext_vector_type(8))) short short8v;   // 8 bf16 = 4 VGPR
typedef __attribute__((ext_vector_type(4))) float f32x4;     // MFMA C/D

__device__ inline unsigned cvt_pk_bf16(float a, float b) {
  unsigned r;
  asm("v_cvt_pk_bf16_f32 %0, %1, %2" : "=v"(r) : "v"(a), "v"(b));
  return r;
}
__device__ inline unsigned short f32_to_bf16(float f) {
  union { float f; unsigned u; } v; v.f = f;
  unsigned r = v.u + 0x7fff + ((v.u >> 16) & 1);   // RNE
  return (unsigned short)(r >> 16);
}
__device__ inline float bf16_to_f32(unsigned short h) {
  union { unsigned u; float f; } v; v.u = ((unsigned)h) << 16;
  return v.f;
}

// ---------------------------------------------------------------------------
// Fused fc1 ∥ stage. fc1 (blocks [0,512)): MFMA 16x16x32 bf16, W1 in VGPRs,
// ZERO LDS -> no resource clash with the stage half (unlike R6's LDS-heavy
// fc1, which made this fusion neutral). stage (blocks [512,768)): bucket
// scatter, LDS = 2x391 ints only. HBM/MFMA-bound ∥ LDS-atomic-bound.
// ---------------------------------------------------------------------------
__global__ __launch_bounds__(256) void fc1_stage_kernel(
    const float* __restrict__ x, const float* __restrict__ w,
    const float* __restrict__ b, unsigned short* __restrict__ h1,
    const int* __restrict__ src, const int* __restrict__ dst,
    int* __restrict__ gcur, int* __restrict__ staged) {
  __shared__ int hist[NB], base[NB];   // used by stage branch only (~3KB)

  if (blockIdx.x < FC1_BLOCKS) {
    // ---------------- fc1 (MFMA) ----------------
    const int lane = threadIdx.x & 63;
    const int o = lane & 15;
    const int kb = lane >> 4;
    const int wid = (blockIdx.x * 256 + threadIdx.x) >> 6;
    const int nwaves = FC1_BLOCKS * 4;

    short8v bf[16];
#pragma unroll
    for (int s = 0; s < 16; ++s) {
      float wv[8];
#pragma unroll
      for (int j = 0; j < 8; ++j) {
        wv[j] = w[(size_t)(s * 32 + kb * 8 + j) * 16 + o];
      }
      union { unsigned u[4]; short8v v; } pk;
      pk.u[0] = cvt_pk_bf16(wv[0], wv[1]);
      pk.u[1] = cvt_pk_bf16(wv[2], wv[3]);
      pk.u[2] = cvt_pk_bf16(wv[4], wv[5]);
      pk.u[3] = cvt_pk_bf16(wv[6], wv[7]);
      bf[s] = pk.v;
    }
    const float bias = b[o];
    const int ntiles = N_NODES / 16;  // 6250

    for (int tile = wid; tile < ntiles; tile += nwaves) {
      const float* xrow = x + (size_t)(tile * 16 + o) * 512 + kb * 8;
      f32x4 c = {0.f, 0.f, 0.f, 0.f};
#pragma unroll
      for (int s = 0; s < 16; ++s) {
        const float4* xp = (const float4*)(xrow + s * 32);
        float4 a0 = xp[0];
        float4 a1 = xp[1];
        union { unsigned u[4]; short8v v; } fa;
        fa.u[0] = cvt_pk_bf16(a0.x, a0.y);
        fa.u[1] = cvt_pk_bf16(a0.z, a0.w);
        fa.u[2] = cvt_pk_bf16(a1.x, a1.y);
        fa.u[3] = cvt_pk_bf16(a1.z, a1.w);
        c = __builtin_amdgcn_mfma_f32_16x16x32_bf16(fa.v, bf[s], c, 0, 0, 0);
      }
      const int rbase = tile * 16 + (lane >> 4) * 4;
#pragma unroll
      for (int j = 0; j < 4; ++j) {
        h1[(size_t)(rbase + j) * 16 + o] = f32_to_bf16(fmaxf(c[j] + bias, 0.f));
      }
    }
  } else {
    // ---------------- stage ----------------
    const int tid = threadIdx.x;
    for (int i = tid; i < NB; i += 256) hist[i] = 0;
    __syncthreads();

    const int sb = blockIdx.x - FC1_BLOCKS;
    const int per = (N_EDGES + STG_BLOCKS - 1) / STG_BLOCKS;
    const int e0 = sb * per;
    const int e1 = min(e0 + per, N_EDGES);

    for (int e = e0 + tid; e < e1; e += 256) {
      atomicAdd(&hist[dst[e] >> BSHIFT], 1);
    }
    __syncthreads();
    for (int bkt = tid; bkt < NB; bkt += 256) {
      int h = hist[bkt];
      base[bkt] = (h > 0) ? atomicAdd(&gcur[bkt], h) : 0;
      hist[bkt] = 0;  // reuse as local cursor
    }
    __syncthreads();
    for (int e = e0 + tid; e < e1; e += 256) {
      int d = dst[e];
      int s = src[e];
      int bkt = d >> BSHIFT;
      int pos = base[bkt] + atomicAdd(&hist[bkt], 1);
      if (pos < CAP) staged[bkt * CAP + pos] = (s << 8) | (d & BMASK);
    }
  }
}

// ---------------------------------------------------------------------------
// finalize: per bucket, LDS-sort staged slice by local dst; offs/cnt out.
// ---------------------------------------------------------------------------
__global__ __launch_bounds__(256) void finalize_kernel(
    int* __restrict__ staged, const int* __restrict__ gcur,
    int* __restrict__ offs, int* __restrict__ cnt) {
  __shared__ int ed[CAP];
  __shared__ int lcnt[NPB];
  __shared__ int lofs[NPB];
  __shared__ int sc[256];
  const int bkt = blockIdx.x, tid = threadIdx.x;
  const int nE = min(gcur[bkt], CAP);
  const int base = bkt * CAP;
  for (int e = tid; e < nE; e += 256) ed[e] = staged[base + e];
  lcnt[tid] = 0;
  __syncthreads();
  for (int e = tid; e < nE; e += 256) atomicAdd(&lcnt[ed[e] & BMASK], 1);
  __syncthreads();
  const int v = lcnt[tid];
  sc[tid] = v;
  __syncthreads();
  for (int d = 1; d < 256; d <<= 1) {
    int add = (tid >= d) ? sc[tid - d] : 0;
    __syncthreads();
    sc[tid] += add;
    __syncthreads();
  }
  const int excl = sc[tid] - v;
  lofs[tid] = excl;
  const int g = bkt * NPB + tid;
  if (g < N_NODES) {
    offs[g] = base + excl;
    cnt[g] = v;
  }
  lcnt[tid] = 0;  // reuse as cursor
  __syncthreads();
  for (int e = tid; e < nE; e += 256) {
    int u = ed[e];
    int dl = u & BMASK;
    int pos = lofs[dl] + atomicAdd(&lcnt[dl], 1);
    staged[base + pos] = u >> 8;  // plain src index, node-sorted
  }
}

// ---------------------------------------------------------------------------
// conv1 (16 -> 32): 8 threads/node, 4-deep unrolled bf16 gather (8B/lane,
// 32B/row -> L2-resident h1). Weight LDS swizzled: store quad Q of row k at
// Q^(k>>2); read original quad q from 4*(q^t), accumulate into p[q].
// ---------------------------------------------------------------------------
__global__ __launch_bounds__(256) void conv1_kernel(
    const unsigned short* __restrict__ h1, const int* __restrict__ csr,
    const int* __restrict__ offs, const int* __restrict__ cnt,
    const float* __restrict__ llw, const float* __restrict__ llb,
    const float* __restrict__ lrw, const float* __restrict__ c2llw,
    float* __restrict__ h2, unsigned short* __restrict__ t2) {
  __shared__ float wl[512], wr[512], w2c[512];
  __shared__ float bb[32];
  for (int idx = threadIdx.x; idx < 512; idx += 256) {
    const int k = idx >> 5, jj = idx & 31;
    const int sj = 4 * ((jj >> 2) ^ (k >> 2)) + (jj & 3);  // swizzle store
    wl[k * 32 + sj] = llw[idx];
    wr[k * 32 + sj] = lrw[idx];
    w2c[idx] = c2llw[idx];  // unswizzled
  }
  if (threadIdx.x < 32) bb[threadIdx.x] = llb[threadIdx.x];
  __syncthreads();

  const int tid = blockIdx.x * 256 + threadIdx.x;
  const int i = tid >> 3;
  if (i >= N_NODES) return;
  const int t8 = threadIdx.x & 7;
  const int gg = t8 >> 2;       // group 0/1
  const int t = t8 & 3;         // dim slice
  const int start = offs[i], deg = cnt[i];

  float4 acc = make_float4(0.f, 0.f, 0.f, 0.f);
  int e = gg;
  for (; e + 6 < deg; e += 8) {
    const int s0 = csr[start + e];
    const int s1 = csr[start + e + 2];
    const int s2 = csr[start + e + 4];
    const int s3 = csr[start + e + 6];
    ushort4 a0 = *(const ushort4*)(h1 + (size_t)s0 * 16 + t * 4);
    ushort4 a1 = *(const ushort4*)(h1 + (size_t)s1 * 16 + t * 4);
    ushort4 a2 = *(const ushort4*)(h1 + (size_t)s2 * 16 + t * 4);
    ushort4 a3 = *(const ushort4*)(h1 + (size_t)s3 * 16 + t * 4);
    acc.x += (bf16_to_f32(a0.x) + bf16_to_f32(a1.x)) +
             (bf16_to_f32(a2.x) + bf16_to_f32(a3.x));
    acc.y += (bf16_to_f32(a0.y) + bf16_to_f32(a1.y)) +
             (bf16_to_f32(a2.y) + bf16_to_f32(a3.y));
    acc.z += (bf16_to_f32(a0.z) + bf16_to_f32(a1.z)) +
             (bf16_to_f32(a2.z) + bf16_to_f32(a3.z));
    acc.w += (bf16_to_f32(a0.w) + bf16_to_f32(a1.w)) +
             (bf16_to_f32(a2.w) + bf16_to_f32(a3.w));
  }
  for (; e < deg; e += 2) {
    const int s = csr[start + e];
    ushort4 a = *(const ushort4*)(h1 + (size_t)s * 16 + t * 4);
    acc.x += bf16_to_f32(a.x); acc.y += bf16_to_f32(a.y);
    acc.z += bf16_to_f32(a.z); acc.w += bf16_to_f32(a.w);
  }
  acc.x += __shfl_xor(acc.x, 4, 64);
  acc.y += __shfl_xor(acc.y, 4, 64);
  acc.z += __shfl_xor(acc.z, 4, 64);
  acc.w += __shfl_xor(acc.w, 4, 64);

  const float inv = 1.f / (float)(deg > 0 ? deg : 1);
  const ushort4 selfu = *(const ushort4*)(h1 + (size_t)i * 16 + t * 4);
  const float mk[4] = {acc.x * inv, acc.y * inv, acc.z * inv, acc.w * inv};
  const float sk[4] = {bf16_to_f32(selfu.x), bf16_to_f32(selfu.y),
                       bf16_to_f32(selfu.z), bf16_to_f32(selfu.w)};

  float4 p[8];
#pragma unroll
  for (int q = 0; q < 8; ++q) p[q] = make_float4(0.f, 0.f, 0.f, 0.f);
#pragma unroll
  for (int j = 0; j < 4; ++j) {
    const int k = 4 * t + j;          // k>>2 == t
#pragma unroll
    for (int q = 0; q < 8; ++q) {
      const int qs = 4 * (q ^ t);     // swizzled position of original quad q
      float4 w4l = *(const float4*)&wl[k * 32 + qs];
      float4 w4r = *(const float4*)&wr[k * 32 + qs];
      p[q].x += mk[j] * w4l.x + sk[j] * w4r.x;
      p[q].y += mk[j] * w4l.y + sk[j] * w4r.y;
      p[q].z += mk[j] * w4l.z + sk[j] * w4r.z;
      p[q].w += mk[j] * w4l.w + sk[j] * w4r.w;
    }
  }
#pragma unroll
  for (int mask = 1; mask <= 2; mask <<= 1) {
#pragma unroll
    for (int q = 0; q < 8; ++q) {
      p[q].x += __shfl_xor(p[q].x, mask, 64);
      p[q].y += __shfl_xor(p[q].y, mask, 64);
      p[q].z += __shfl_xor(p[q].z, mask, 64);
      p[q].w += __shfl_xor(p[q].w, mask, 64);
    }
  }
  float o[32];
#pragma unroll
  for (int q = 0; q < 8; ++q) {
    o[4 * q + 0] = fmaxf(p[q].x + bb[4 * q + 0], 0.f);
    o[4 * q + 1] = fmaxf(p[q].y + bb[4 * q + 1], 0.f);
    o[4 * q + 2] = fmaxf(p[q].z + bb[4 * q + 2], 0.f);
    o[4 * q + 3] = fmaxf(p[q].w + bb[4 * q + 3], 0.f);
  }
  *(float4*)(h2 + (size_t)i * 32 + 4 * t8) =
      make_float4(o[4 * t8], o[4 * t8 + 1], o[4 * t8 + 2], o[4 * t8 + 3]);
  float t0 = 0.f, t1 = 0.f;
#pragma unroll
  for (int k = 0; k < 32; ++k) {
    const float ok = o[k];
    t0 += ok * w2c[k * 16 + 2 * t8];
    t1 += ok * w2c[k * 16 + 2 * t8 + 1];
  }
  *(unsigned*)(t2 + (size_t)i * 16 + 2 * t8) = cvt_pk_bf16(t0, t1);
}

// ---------------------------------------------------------------------------
// conv2 (pre-transformed bf16 t2, 16-dim agg) + fc2 + head -> d_out.
// ---------------------------------------------------------------------------
__global__ __launch_bounds__(256) void conv2_kernel(
    const unsigned short* __restrict__ t2, const float* __restrict__ h2,
    const int* __restrict__ csr, const int* __restrict__ offs,
    const int* __restrict__ cnt, const float* __restrict__ llb,
    const float* __restrict__ lrw, const float* __restrict__ fc2w,
    const float* __restrict__ fc2b, float* __restrict__ out) {
  __shared__ float wr[512];
  __shared__ float bb[16];
  __shared__ float w2[48];
  __shared__ float b2[3];
  for (int idx = threadIdx.x; idx < 512; idx += 256) {
    const int k = idx >> 4, jj = idx & 15;
    const int sj = 4 * ((jj >> 2) ^ ((k >> 2) & 3)) + (jj & 3);  // swizzle
    wr[k * 16 + sj] = lrw[idx];
  }
  if (threadIdx.x < 16) bb[threadIdx.x] = llb[threadIdx.x];
  else if (threadIdx.x >= 64 && threadIdx.x < 112) w2[threadIdx.x - 64] = fc2w[threadIdx.x - 64];
  else if (threadIdx.x >= 128 && threadIdx.x < 131) b2[threadIdx.x - 128] = fc2b[threadIdx.x - 128];
  __syncthreads();

  const int tid = blockIdx.x * 256 + threadIdx.x;
  const int i = tid >> 3;
  if (i >= N_NODES) return;
  const int t8 = threadIdx.x & 7;
  const int gg = t8 >> 2;
  const int t = t8 & 3;
  const int start = offs[i], deg = cnt[i];

  float4 acc = make_float4(0.f, 0.f, 0.f, 0.f);
  int e = gg;
  for (; e + 6 < deg; e += 8) {
    const int s0 = csr[start + e];
    const int s1 = csr[start + e + 2];
    const int s2 = csr[start + e + 4];
    const int s3 = csr[start + e + 6];
    ushort4 a0 = *(const ushort4*)(t2 + (size_t)s0 * 16 + t * 4);
    ushort4 a1 = *(const ushort4*)(t2 + (size_t)s1 * 16 + t * 4);
    ushort4 a2 = *(const ushort4*)(t2 + (size_t)s2 * 16 + t * 4);
    ushort4 a3 = *(const ushort4*)(t2 + (size_t)s3 * 16 + t * 4);
    acc.x += (bf16_to_f32(a0.x) + bf16_to_f32(a1.x)) +
             (bf16_to_f32(a2.x) + bf16_to_f32(a3.x));
    acc.y += (bf16_to_f32(a0.y) + bf16_to_f32(a1.y)) +
             (bf16_to_f32(a2.y) + bf16_to_f32(a3.y));
    acc.z += (bf16_to_f32(a0.z) + bf16_to_f32(a1.z)) +
             (bf16_to_f32(a2.z) + bf16_to_f32(a3.z));
    acc.w += (bf16_to_f32(a0.w) + bf16_to_f32(a1.w)) +
             (bf16_to_f32(a2.w) + bf16_to_f32(a3.w));
  }
  for (; e < deg; e += 2) {
    const int s = csr[start + e];
    ushort4 a = *(const ushort4*)(t2 + (size_t)s * 16 + t * 4);
    acc.x += bf16_to_f32(a.x); acc.y += bf16_to_f32(a.y);
    acc.z += bf16_to_f32(a.z); acc.w += bf16_to_f32(a.w);
  }
  acc.x += __shfl_xor(acc.x, 4, 64);
  acc.y += __shfl_xor(acc.y, 4, 64);
  acc.z += __shfl_xor(acc.z, 4, 64);
  acc.w += __shfl_xor(acc.w, 4, 64);

  const float inv = 1.f / (float)(deg > 0 ? deg : 1);
  const float4 s0v = *(const float4*)(h2 + (size_t)i * 32 + 4 * t8);
  const float sk[4] = {s0v.x, s0v.y, s0v.z, s0v.w};
  float4 p[4];
#pragma unroll
  for (int q = 0; q < 4; ++q) p[q] = make_float4(0.f, 0.f, 0.f, 0.f);
#pragma unroll
  for (int kk = 0; kk < 4; ++kk) {
    const int k = 4 * t8 + kk;        // (k>>2)&3 == t8&3
    const float s = sk[kk];
#pragma unroll
    for (int q = 0; q < 4; ++q) {
      const int qs = 4 * (q ^ (t8 & 3));  // swizzled position of quad q
      const float4 wv = *(const float4*)&wr[k * 16 + qs];
      p[q].x += s * wv.x; p[q].y += s * wv.y;
      p[q].z += s * wv.z; p[q].w += s * wv.w;
    }
  }
  if (gg == 0) {
    p[t].x += acc.x * inv; p[t].y += acc.y * inv;
    p[t].z += acc.z * inv; p[t].w += acc.w * inv;
  }
#pragma unroll
  for (int mask = 1; mask <= 4; mask <<= 1) {
#pragma unroll
    for (int q = 0; q < 4; ++q) {
      p[q].x += __shfl_xor(p[q].x, mask, 64);
      p[q].y += __shfl_xor(p[q].y, mask, 64);
      p[q].z += __shfl_xor(p[q].z, mask, 64);
      p[q].w += __shfl_xor(p[q].w, mask, 64);
    }
  }
  if (t8 < 3) {
    float f[16];
#pragma unroll
    for (int q = 0; q < 4; ++q) {
      f[4 * q + 0] = fmaxf(p[q].x + bb[4 * q + 0], 0.f);
      f[4 * q + 1] = fmaxf(p[q].y + bb[4 * q + 1], 0.f);
      f[4 * q + 2] = fmaxf(p[q].z + bb[4 * q + 2], 0.f);
      f[4 * q + 3] = fmaxf(p[q].w + bb[4 * q + 3], 0.f);
    }
    float v0 = b2[0], v1 = b2[1], v2 = b2[2];
#pragma unroll
    for (int k = 0; k < 16; ++k) {
      v0 += f[k] * w2[k * 3 + 0];
      v1 += f[k] * w2[k * 3 + 1];
      v2 += f[k] * w2[k * 3 + 2];
    }
    float gsi = 1.f / (1.f + expf(-v1));
    float mxi = 1.f / (1.f + expf(-v2));
    float fsi = fmaxf(v0, 0.f) + gsi;
    float rv = (t8 == 0) ? fsi : ((t8 == 1) ? gsi : mxi);
    out[(size_t)i * 3 + t8] = rv;
  }
}

extern "C" void kernel_launch(void* const* d_in, const int* in_sizes, int n_in,
                              void* d_out, int out_size, void* d_ws, size_t ws_size,
                              hipStream_t stream) {
  const float* x = (const float*)d_in[0];
  const int* ei = (const int*)d_in[1];
  const float* fc1w = (const float*)d_in[2];
  const float* fc1b = (const float*)d_in[3];
  const float* c1llw = (const float*)d_in[4];
  const float* c1llb = (const float*)d_in[5];
  const float* c1lrw = (const float*)d_in[6];
  const float* c2llw = (const float*)d_in[7];
  const float* c2llb = (const float*)d_in[8];
  const float* c2lrw = (const float*)d_in[9];
  const float* fc2w = (const float*)d_in[10];
  const float* fc2b = (const float*)d_in[11];
  float* outp = (float*)d_out;
  const int* src = ei;
  const int* dst = ei + N_EDGES;

  char* ws = (char*)d_ws;
  unsigned short* h1 = (unsigned short*)ws;  ws += (size_t)N_NODES * 16 * 2;
  float* h2 = (float*)ws;                    ws += (size_t)N_NODES * 32 * 4;
  unsigned short* t2 = (unsigned short*)ws;  ws += (size_t)N_NODES * 16 * 2;
  int* staged = (int*)ws;                    ws += (size_t)NB * CAP * 4;
  int* gcur = (int*)ws;                      ws += (size_t)NB * 4;
  int* offs = (int*)ws;                      ws += (size_t)N_NODES * 4;
  int* cnt = (int*)ws;                       ws += (size_t)N_NODES * 4;
  (void)ws_size; (void)n_in; (void)in_sizes; (void)out_size;

  hipMemsetAsync(gcur, 0, (size_t)NB * 4, stream);
  fc1_stage_kernel<<<FC1_BLOCKS + STG_BLOCKS, 256, 0, stream>>>(
      x, fc1w, fc1b, h1, src, dst, gcur, staged);
  finalize_kernel<<<NB, 256, 0, stream>>>(staged, gcur, offs, cnt);
  conv1_kernel<<<(N_NODES * 8 + 255) / 256, 256, 0, stream>>>(
      h1, staged, offs, cnt, c1llw, c1llb, c1lrw, c2llw, h2, t2);
  conv2_kernel<<<(N_NODES * 8 + 255) / 256, 256, 0, stream>>>(
      t2, h2, staged, offs, cnt, c2llb, c2lrw, fc2w, fc2b, outp);
}